// Round 1
// baseline (776.842 us; speedup 1.0000x reference)
//
#include <hip/hip_runtime.h>
#include <hip/hip_bf16.h>
#include <math.h>

#define Nn 20000
#define Ee 320000
#define INF_ 256
#define Hh 4
#define Cc 64
#define HC 256
#define NEG_SLOPE 0.2f

// ---------------- CSR build ----------------

__global__ void init_deg(int* deg, int n) {
    int i = blockIdx.x * blockDim.x + threadIdx.x;
    if (i < n) deg[i] = 1;  // self-loop pre-counted
}

__global__ void hist_kernel(const int* __restrict__ dst, int ne, int* deg) {
    int e = blockIdx.x * blockDim.x + threadIdx.x;
    if (e < ne) atomicAdd(&deg[dst[e]], 1);
}

// single-wave exclusive scan over n entries (n ~ 20000, trivial time)
__global__ void scan_kernel(const int* __restrict__ deg, int* row_start, int* cursor, int n) {
    int lane = threadIdx.x;  // 64 threads, 1 block
    int carry = 0;
    for (int base = 0; base < n; base += 64) {
        int i = base + lane;
        int v = (i < n) ? deg[i] : 0;
        int x = v;
        #pragma unroll
        for (int off = 1; off < 64; off <<= 1) {
            int y = __shfl_up(x, off, 64);
            if (lane >= off) x += y;
        }
        int excl = carry + x - v;
        if (i < n) { row_start[i] = excl; cursor[i] = excl; }
        carry += __shfl(x, 63, 64);
    }
    if (lane == 0) row_start[n] = carry;
}

__global__ void scatter_kernel(const int* __restrict__ src, const int* __restrict__ dst,
                               int ne, int n, int* cursor, int* colx) {
    int e = blockIdx.x * blockDim.x + threadIdx.x;
    if (e < ne) {
        int d = dst[e];
        int pos = atomicAdd(&cursor[d], 1);
        colx[pos] = src[e];
    } else if (e < ne + n) {
        int node = e - ne;
        int pos = atomicAdd(&cursor[node], 1);
        colx[pos] = node;  // self-loop
    }
}

// ---------------- fp32 SGEMM: C[M,Nc] = A[M,K] @ W[K,Nc] ----------------
// 64x64 tile, 256 threads, 4x4 micro-tile, TK=16.

#define GTM 64
#define GTN 64
#define GTK 16

__global__ __launch_bounds__(256) void gemm_kernel(const float* __restrict__ A,
                                                   const float* __restrict__ W,
                                                   float* __restrict__ Cb,
                                                   int M, int K, int Nc) {
    __shared__ float As[GTK][GTM + 1];
    __shared__ float Bs[GTK][GTN + 1];
    int tid = threadIdx.x;
    int bm = blockIdx.y * GTM;
    int bn = blockIdx.x * GTN;
    int tx = tid % 16;  // n dim
    int ty = tid / 16;  // m dim
    float accv[4][4] = {};
    for (int k0 = 0; k0 < K; k0 += GTK) {
        #pragma unroll
        for (int i = 0; i < 4; ++i) {
            int idx = tid + i * 256;          // 0..1023 over 64x16 A tile
            int m = idx / GTK;
            int k = idx % GTK;
            int gm = bm + m;
            As[k][m] = (gm < M) ? A[(size_t)gm * K + k0 + k] : 0.f;
        }
        #pragma unroll
        for (int i = 0; i < 4; ++i) {
            int idx = tid + i * 256;          // 0..1023 over 16x64 B tile
            int k = idx / GTN;
            int n = idx % GTN;
            Bs[k][n] = W[(size_t)(k0 + k) * Nc + bn + n];
        }
        __syncthreads();
        #pragma unroll
        for (int k = 0; k < GTK; ++k) {
            float av[4], bv[4];
            #pragma unroll
            for (int i = 0; i < 4; ++i) av[i] = As[k][ty * 4 + i];
            #pragma unroll
            for (int j = 0; j < 4; ++j) bv[j] = Bs[k][tx * 4 + j];
            #pragma unroll
            for (int i = 0; i < 4; ++i)
                #pragma unroll
                for (int j = 0; j < 4; ++j) accv[i][j] += av[i] * bv[j];
        }
        __syncthreads();
    }
    #pragma unroll
    for (int i = 0; i < 4; ++i) {
        int gm = bm + ty * 4 + i;
        if (gm >= M) continue;
        #pragma unroll
        for (int j = 0; j < 4; ++j)
            Cb[(size_t)gm * Nc + bn + tx * 4 + j] = accv[i][j];
    }
}

// ---------------- GATv2 edge phase: one block per dst node ----------------
// 256 threads: wave = head (4 waves), lane = channel within head.
// Online softmax per head; aggregation atomic-free.

__global__ __launch_bounds__(256) void gat_kernel(const float* __restrict__ XL,
                                                  const float* __restrict__ XR,
                                                  const int* __restrict__ row_start,
                                                  const int* __restrict__ colx,
                                                  const float* __restrict__ att,
                                                  const float* __restrict__ bias,
                                                  float* __restrict__ Hout,
                                                  int relu_flag) {
    int node = blockIdx.x;
    int ch = threadIdx.x;                 // 0..255 = head*64 + c
    float xr = XR[(size_t)node * HC + ch];
    float a  = att[ch];                   // att (H,C) row-major flat == ch
    int e0 = row_start[node], e1 = row_start[node + 1];
    float m = -1e30f, l = 0.f, acc = 0.f;
    for (int e = e0; e < e1; ++e) {
        int s = colx[e];
        float v = XL[(size_t)s * HC + ch];
        float t = v + xr;
        t = (t > 0.f) ? t : NEG_SLOPE * t;
        float p = a * t;
        #pragma unroll
        for (int off = 32; off > 0; off >>= 1) p += __shfl_xor(p, off, 64);
        float sc = p;                     // per-head score, all lanes
        float mn = fmaxf(m, sc);
        float scale = __expf(m - mn);
        float pe = __expf(sc - mn);
        l = l * scale + pe;
        acc = acc * scale + pe * v;
        m = mn;
    }
    float o = acc / l + bias[ch];
    if (relu_flag) o = fmaxf(o, 0.f);
    Hout[(size_t)node * HC + ch] = o;
}

// ---------------- pooling + FC ----------------

__global__ void zero_f(float* p, int n) {
    int i = blockIdx.x * blockDim.x + threadIdx.x;
    if (i < n) p[i] = 0.f;
}

__global__ __launch_bounds__(256) void colsum_kernel(const float* __restrict__ Hmat,
                                                     float* __restrict__ g, int n) {
    int ch = threadIdx.x;
    float s = 0.f;
    for (int r = blockIdx.x; r < n; r += gridDim.x)
        s += Hmat[(size_t)r * HC + ch];
    atomicAdd(&g[ch], s);
}

__global__ __launch_bounds__(256) void fc_kernel(const float* __restrict__ g,
                                                 const float* __restrict__ Wfc,
                                                 const float* __restrict__ bfc,
                                                 float* __restrict__ out, float invN) {
    int t = threadIdx.x;
    float gv = g[t] * invN;
    float p0 = gv * Wfc[2 * t];
    float p1 = gv * Wfc[2 * t + 1];
    #pragma unroll
    for (int off = 32; off > 0; off >>= 1) {
        p0 += __shfl_xor(p0, off, 64);
        p1 += __shfl_xor(p1, off, 64);
    }
    __shared__ float s0[4], s1[4];
    if ((t & 63) == 0) { s0[t >> 6] = p0; s1[t >> 6] = p1; }
    __syncthreads();
    if (t == 0) {
        out[0] = s0[0] + s0[1] + s0[2] + s0[3] + bfc[0];
        out[1] = s1[0] + s1[1] + s1[2] + s1[3] + bfc[1];
    }
}

// ---------------- launch ----------------

extern "C" void kernel_launch(void* const* d_in, const int* in_sizes, int n_in,
                              void* d_out, int out_size, void* d_ws, size_t ws_size,
                              hipStream_t stream) {
    const float* x    = (const float*)d_in[0];
    const int*   eidx = (const int*)d_in[1];   // (2,E) row-major: [src | dst]
    const float* Wl1  = (const float*)d_in[2];
    const float* Wr1  = (const float*)d_in[3];
    const float* att1 = (const float*)d_in[4];
    const float* b1   = (const float*)d_in[5];
    const float* Wl2  = (const float*)d_in[6];
    const float* Wr2  = (const float*)d_in[7];
    const float* att2 = (const float*)d_in[8];
    const float* b2   = (const float*)d_in[9];
    const float* Wfc  = (const float*)d_in[10];
    const float* bfc  = (const float*)d_in[11];
    float* out = (float*)d_out;

    const int* srcv = eidx;
    const int* dstv = eidx + Ee;

    // workspace layout (~63 MB)
    size_t NHC = (size_t)Nn * HC;
    float* XL = (float*)d_ws;
    float* XR = XL + NHC;
    float* Hb = XR + NHC;
    float* g  = Hb + NHC;
    int* deg       = (int*)(g + HC);
    int* row_start = deg + Nn;
    int* cursor    = row_start + (Nn + 1);
    int* colx      = cursor + Nn;          // Ee + Nn entries

    // CSR build
    init_deg<<<(Nn + 255) / 256, 256, 0, stream>>>(deg, Nn);
    hist_kernel<<<(Ee + 255) / 256, 256, 0, stream>>>(dstv, Ee, deg);
    scan_kernel<<<1, 64, 0, stream>>>(deg, row_start, cursor, Nn);
    scatter_kernel<<<(Ee + Nn + 255) / 256, 256, 0, stream>>>(srcv, dstv, Ee, Nn, cursor, colx);

    dim3 ggrid(HC / GTN, (Nn + GTM - 1) / GTM);

    // layer 1
    gemm_kernel<<<ggrid, 256, 0, stream>>>(x, Wl1, XL, Nn, INF_, HC);
    gemm_kernel<<<ggrid, 256, 0, stream>>>(x, Wr1, XR, Nn, INF_, HC);
    gat_kernel<<<Nn, 256, 0, stream>>>(XL, XR, row_start, colx, att1, b1, Hb, 1);

    // layer 2
    gemm_kernel<<<ggrid, 256, 0, stream>>>(Hb, Wl2, XL, Nn, HC, HC);
    gemm_kernel<<<ggrid, 256, 0, stream>>>(Hb, Wr2, XR, Nn, HC, HC);
    gat_kernel<<<Nn, 256, 0, stream>>>(XL, XR, row_start, colx, att2, b2, Hb, 1);

    // pool + fc
    zero_f<<<1, 256, 0, stream>>>(g, HC);
    colsum_kernel<<<256, 256, 0, stream>>>(Hb, g, Nn);
    fc_kernel<<<1, 256, 0, stream>>>(g, Wfc, bfc, out, 1.0f / Nn);
}

// Round 2
// 634.768 us; speedup vs baseline: 1.2238x; 1.2238x over previous
//
#include <hip/hip_runtime.h>
#include <hip/hip_bf16.h>
#include <math.h>

#define Nn 20000
#define Ee 320000
#define INF_ 256
#define Hh 4
#define Cc 64
#define HC 256
#define NEG_SLOPE 0.2f

// ---------------- CSR build ----------------

__global__ void init_deg(int* deg, int n) {
    int i = blockIdx.x * blockDim.x + threadIdx.x;
    if (i < n) deg[i] = 1;  // self-loop pre-counted
}

__global__ void hist_kernel(const int* __restrict__ dst, int ne, int* deg) {
    int e = blockIdx.x * blockDim.x + threadIdx.x;
    if (e < ne) atomicAdd(&deg[dst[e]], 1);
}

// hierarchical scan, phase 1: per-block (256 elems) exclusive scan + block sum
__global__ __launch_bounds__(256) void scan1(const int* __restrict__ deg,
                                             int* __restrict__ excl,
                                             int* __restrict__ bsum, int n) {
    int tid = threadIdx.x;
    int gid = blockIdx.x * 256 + tid;
    int lane = tid & 63;
    int v = (gid < n) ? deg[gid] : 0;
    int x = v;
    #pragma unroll
    for (int off = 1; off < 64; off <<= 1) {
        int y = __shfl_up(x, off, 64);
        if (lane >= off) x += y;
    }
    __shared__ int wsum[4];
    if (lane == 63) wsum[tid >> 6] = x;
    __syncthreads();
    int wadd = 0;
    for (int w = 0; w < (tid >> 6); ++w) wadd += wsum[w];
    int incl = x + wadd;
    if (gid < n) excl[gid] = incl - v;
    if (tid == 255) bsum[blockIdx.x] = incl;
}

// phase 2: single-wave scan over block sums (nb ~ 79 -> 2 iters)
__global__ void scan2(const int* __restrict__ bsum, int* __restrict__ boff, int nb) {
    int lane = threadIdx.x;
    int carry = 0;
    for (int base = 0; base < nb; base += 64) {
        int i = base + lane;
        int v = (i < nb) ? bsum[i] : 0;
        int x = v;
        #pragma unroll
        for (int off = 1; off < 64; off <<= 1) {
            int y = __shfl_up(x, off, 64);
            if (lane >= off) x += y;
        }
        if (i < nb) boff[i] = carry + x - v;
        carry += __shfl(x, 63, 64);
    }
    if (lane == 0) boff[nb] = carry;
}

// phase 3: add block offsets, produce row_start + cursor (+ total at [n])
__global__ void scan_add(int* __restrict__ row_start, int* __restrict__ cursor,
                         const int* __restrict__ boff, int n, int nb) {
    int gid = blockIdx.x * blockDim.x + threadIdx.x;
    if (gid < n) {
        int v = row_start[gid] + boff[gid >> 8];
        row_start[gid] = v;
        cursor[gid] = v;
    }
    if (gid == n) row_start[n] = boff[nb];
}

__global__ void scatter_kernel(const int* __restrict__ src, const int* __restrict__ dst,
                               int ne, int n, int* cursor, int* colx) {
    int e = blockIdx.x * blockDim.x + threadIdx.x;
    if (e < ne) {
        int d = dst[e];
        int pos = atomicAdd(&cursor[d], 1);
        colx[pos] = src[e];
    } else if (e < ne + n) {
        int node = e - ne;
        int pos = atomicAdd(&cursor[node], 1);
        colx[pos] = node;  // self-loop
    }
}

// ---------------- fp32 SGEMM: C[M,Nc] = A[M,K] @ W[K,Nc] ----------------
// 64x64 tile, 256 threads, 4x4 micro-tile, TK=16.

#define GTM 64
#define GTN 64
#define GTK 16

__global__ __launch_bounds__(256) void gemm_kernel(const float* __restrict__ A,
                                                   const float* __restrict__ W,
                                                   float* __restrict__ Cb,
                                                   int M, int K, int Nc) {
    __shared__ float As[GTK][GTM + 1];
    __shared__ float Bs[GTK][GTN + 1];
    int tid = threadIdx.x;
    int bm = blockIdx.y * GTM;
    int bn = blockIdx.x * GTN;
    int tx = tid % 16;  // n dim
    int ty = tid / 16;  // m dim
    float accv[4][4] = {};
    for (int k0 = 0; k0 < K; k0 += GTK) {
        #pragma unroll
        for (int i = 0; i < 4; ++i) {
            int idx = tid + i * 256;          // 0..1023 over 64x16 A tile
            int m = idx / GTK;
            int k = idx % GTK;
            int gm = bm + m;
            As[k][m] = (gm < M) ? A[(size_t)gm * K + k0 + k] : 0.f;
        }
        #pragma unroll
        for (int i = 0; i < 4; ++i) {
            int idx = tid + i * 256;          // 0..1023 over 16x64 B tile
            int k = idx / GTN;
            int n = idx % GTN;
            Bs[k][n] = W[(size_t)(k0 + k) * Nc + bn + n];
        }
        __syncthreads();
        #pragma unroll
        for (int k = 0; k < GTK; ++k) {
            float av[4], bv[4];
            #pragma unroll
            for (int i = 0; i < 4; ++i) av[i] = As[k][ty * 4 + i];
            #pragma unroll
            for (int j = 0; j < 4; ++j) bv[j] = Bs[k][tx * 4 + j];
            #pragma unroll
            for (int i = 0; i < 4; ++i)
                #pragma unroll
                for (int j = 0; j < 4; ++j) accv[i][j] += av[i] * bv[j];
        }
        __syncthreads();
    }
    #pragma unroll
    for (int i = 0; i < 4; ++i) {
        int gm = bm + ty * 4 + i;
        if (gm >= M) continue;
        #pragma unroll
        for (int j = 0; j < 4; ++j)
            Cb[(size_t)gm * Nc + bn + tx * 4 + j] = accv[i][j];
    }
}

// ---------------- GATv2 edge phase: one block per dst node ----------------
// 256 threads: wave = head (4 waves), lane = channel within head.
// Online softmax per head; aggregation atomic-free.

__global__ __launch_bounds__(256) void gat_kernel(const float* __restrict__ XL,
                                                  const float* __restrict__ XR,
                                                  const int* __restrict__ row_start,
                                                  const int* __restrict__ colx,
                                                  const float* __restrict__ att,
                                                  const float* __restrict__ bias,
                                                  float* __restrict__ Hout,
                                                  int relu_flag) {
    int node = blockIdx.x;
    int ch = threadIdx.x;                 // 0..255 = head*64 + c
    float xr = XR[(size_t)node * HC + ch];
    float a  = att[ch];                   // att (H,C) row-major flat == ch
    int e0 = row_start[node], e1 = row_start[node + 1];
    float m = -1e30f, l = 0.f, acc = 0.f;
    for (int e = e0; e < e1; ++e) {
        int s = colx[e];
        float v = XL[(size_t)s * HC + ch];
        float t = v + xr;
        t = (t > 0.f) ? t : NEG_SLOPE * t;
        float p = a * t;
        #pragma unroll
        for (int off = 32; off > 0; off >>= 1) p += __shfl_xor(p, off, 64);
        float sc = p;                     // per-head score, all lanes
        float mn = fmaxf(m, sc);
        float scale = __expf(m - mn);
        float pe = __expf(sc - mn);
        l = l * scale + pe;
        acc = acc * scale + pe * v;
        m = mn;
    }
    float o = acc / l + bias[ch];
    if (relu_flag) o = fmaxf(o, 0.f);
    Hout[(size_t)node * HC + ch] = o;
}

// ---------------- pooling + FC ----------------

__global__ void zero_f(float* p, int n) {
    int i = blockIdx.x * blockDim.x + threadIdx.x;
    if (i < n) p[i] = 0.f;
}

__global__ __launch_bounds__(256) void colsum_kernel(const float* __restrict__ Hmat,
                                                     float* __restrict__ g, int n) {
    int ch = threadIdx.x;
    float s = 0.f;
    for (int r = blockIdx.x; r < n; r += gridDim.x)
        s += Hmat[(size_t)r * HC + ch];
    atomicAdd(&g[ch], s);
}

__global__ __launch_bounds__(256) void fc_kernel(const float* __restrict__ g,
                                                 const float* __restrict__ Wfc,
                                                 const float* __restrict__ bfc,
                                                 float* __restrict__ out, float invN) {
    int t = threadIdx.x;
    float gv = g[t] * invN;
    float p0 = gv * Wfc[2 * t];
    float p1 = gv * Wfc[2 * t + 1];
    #pragma unroll
    for (int off = 32; off > 0; off >>= 1) {
        p0 += __shfl_xor(p0, off, 64);
        p1 += __shfl_xor(p1, off, 64);
    }
    __shared__ float s0[4], s1[4];
    if ((t & 63) == 0) { s0[t >> 6] = p0; s1[t >> 6] = p1; }
    __syncthreads();
    if (t == 0) {
        out[0] = s0[0] + s0[1] + s0[2] + s0[3] + bfc[0];
        out[1] = s1[0] + s1[1] + s1[2] + s1[3] + bfc[1];
    }
}

// ---------------- launch ----------------

extern "C" void kernel_launch(void* const* d_in, const int* in_sizes, int n_in,
                              void* d_out, int out_size, void* d_ws, size_t ws_size,
                              hipStream_t stream) {
    const float* x    = (const float*)d_in[0];
    const int*   eidx = (const int*)d_in[1];   // (2,E) row-major: [src | dst]
    const float* Wl1  = (const float*)d_in[2];
    const float* Wr1  = (const float*)d_in[3];
    const float* att1 = (const float*)d_in[4];
    const float* b1   = (const float*)d_in[5];
    const float* Wl2  = (const float*)d_in[6];
    const float* Wr2  = (const float*)d_in[7];
    const float* att2 = (const float*)d_in[8];
    const float* b2   = (const float*)d_in[9];
    const float* Wfc  = (const float*)d_in[10];
    const float* bfc  = (const float*)d_in[11];
    float* out = (float*)d_out;

    const int* srcv = eidx;
    const int* dstv = eidx + Ee;

    // workspace layout (~63 MB)
    size_t NHC = (size_t)Nn * HC;
    float* XL = (float*)d_ws;
    float* XR = XL + NHC;
    float* Hb = XR + NHC;
    float* g  = Hb + NHC;
    int* deg       = (int*)(g + HC);
    int* row_start = deg + Nn;
    int* cursor    = row_start + (Nn + 1);
    int* colx      = cursor + Nn;              // Ee + Nn entries
    int* bsum      = colx + (Ee + Nn);
    int* boff      = bsum + 128;               // NB+1 entries

    const int NB = (Nn + 255) / 256;           // 79

    // CSR build
    init_deg<<<(Nn + 255) / 256, 256, 0, stream>>>(deg, Nn);
    hist_kernel<<<(Ee + 255) / 256, 256, 0, stream>>>(dstv, Ee, deg);
    scan1<<<NB, 256, 0, stream>>>(deg, row_start, bsum, Nn);
    scan2<<<1, 64, 0, stream>>>(bsum, boff, NB);
    scan_add<<<(Nn + 256) / 256, 256, 0, stream>>>(row_start, cursor, boff, Nn, NB);
    scatter_kernel<<<(Ee + Nn + 255) / 256, 256, 0, stream>>>(srcv, dstv, Ee, Nn, cursor, colx);

    dim3 ggrid(HC / GTN, (Nn + GTM - 1) / GTM);

    // layer 1
    gemm_kernel<<<ggrid, 256, 0, stream>>>(x, Wl1, XL, Nn, INF_, HC);
    gemm_kernel<<<ggrid, 256, 0, stream>>>(x, Wr1, XR, Nn, INF_, HC);
    gat_kernel<<<Nn, 256, 0, stream>>>(XL, XR, row_start, colx, att1, b1, Hb, 1);

    // layer 2
    gemm_kernel<<<ggrid, 256, 0, stream>>>(Hb, Wl2, XL, Nn, HC, HC);
    gemm_kernel<<<ggrid, 256, 0, stream>>>(Hb, Wr2, XR, Nn, HC, HC);
    gat_kernel<<<Nn, 256, 0, stream>>>(XL, XR, row_start, colx, att2, b2, Hb, 1);

    // pool + fc
    zero_f<<<1, 256, 0, stream>>>(g, HC);
    colsum_kernel<<<256, 256, 0, stream>>>(Hb, g, Nn);
    fc_kernel<<<1, 256, 0, stream>>>(g, Wfc, bfc, out, 1.0f / Nn);
}

// Round 3
// 511.860 us; speedup vs baseline: 1.5177x; 1.2401x over previous
//
#include <hip/hip_runtime.h>
#include <hip/hip_bf16.h>
#include <math.h>

#define Nn 20000
#define Ee 320000
#define INF_ 256
#define Hh 4
#define Cc 64
#define HC 256
#define NEG_SLOPE 0.2f

// ---------------- CSR build ----------------

__global__ void init_deg(int* deg, int n) {
    int i = blockIdx.x * blockDim.x + threadIdx.x;
    if (i < n) deg[i] = 1;  // self-loop pre-counted
}

__global__ void hist_kernel(const int* __restrict__ dst, int ne, int* deg) {
    int e = blockIdx.x * blockDim.x + threadIdx.x;
    if (e < ne) atomicAdd(&deg[dst[e]], 1);
}

// hierarchical scan, phase 1: per-block (256 elems) exclusive scan + block sum
__global__ __launch_bounds__(256) void scan1(const int* __restrict__ deg,
                                             int* __restrict__ excl,
                                             int* __restrict__ bsum, int n) {
    int tid = threadIdx.x;
    int gid = blockIdx.x * 256 + tid;
    int lane = tid & 63;
    int v = (gid < n) ? deg[gid] : 0;
    int x = v;
    #pragma unroll
    for (int off = 1; off < 64; off <<= 1) {
        int y = __shfl_up(x, off, 64);
        if (lane >= off) x += y;
    }
    __shared__ int wsum[4];
    if (lane == 63) wsum[tid >> 6] = x;
    __syncthreads();
    int wadd = 0;
    for (int w = 0; w < (tid >> 6); ++w) wadd += wsum[w];
    int incl = x + wadd;
    if (gid < n) excl[gid] = incl - v;
    if (tid == 255) bsum[blockIdx.x] = incl;
}

// phase 2: single-wave scan over block sums (nb ~ 79 -> 2 iters)
__global__ void scan2(const int* __restrict__ bsum, int* __restrict__ boff, int nb) {
    int lane = threadIdx.x;
    int carry = 0;
    for (int base = 0; base < nb; base += 64) {
        int i = base + lane;
        int v = (i < nb) ? bsum[i] : 0;
        int x = v;
        #pragma unroll
        for (int off = 1; off < 64; off <<= 1) {
            int y = __shfl_up(x, off, 64);
            if (lane >= off) x += y;
        }
        if (i < nb) boff[i] = carry + x - v;
        carry += __shfl(x, 63, 64);
    }
    if (lane == 0) boff[nb] = carry;
}

// phase 3: add block offsets, produce row_start + cursor (+ total at [n])
__global__ void scan_add(int* __restrict__ row_start, int* __restrict__ cursor,
                         const int* __restrict__ boff, int n, int nb) {
    int gid = blockIdx.x * blockDim.x + threadIdx.x;
    if (gid < n) {
        int v = row_start[gid] + boff[gid >> 8];
        row_start[gid] = v;
        cursor[gid] = v;
    }
    if (gid == n) row_start[n] = boff[nb];
}

__global__ void scatter_kernel(const int* __restrict__ src, const int* __restrict__ dst,
                               int ne, int n, int* cursor, int* colx) {
    int e = blockIdx.x * blockDim.x + threadIdx.x;
    if (e < ne) {
        int d = dst[e];
        int pos = atomicAdd(&cursor[d], 1);
        colx[pos] = src[e];
    } else if (e < ne + n) {
        int node = e - ne;
        int pos = atomicAdd(&cursor[node], 1);
        colx[pos] = node;  // self-loop
    }
}

// ---------------- fp32 SGEMM: C[M,Nc] = A[M,K] @ W[K,Nc] ----------------
// 64x64 tile, 256 threads, 4x4 micro-tile, TK=16.

#define GTM 64
#define GTN 64
#define GTK 16

__global__ __launch_bounds__(256) void gemm_kernel(const float* __restrict__ A,
                                                   const float* __restrict__ W,
                                                   float* __restrict__ Cb,
                                                   int M, int K, int Nc) {
    __shared__ float As[GTK][GTM + 1];
    __shared__ float Bs[GTK][GTN + 1];
    int tid = threadIdx.x;
    int bm = blockIdx.y * GTM;
    int bn = blockIdx.x * GTN;
    int tx = tid % 16;  // n dim
    int ty = tid / 16;  // m dim
    float accv[4][4] = {};
    for (int k0 = 0; k0 < K; k0 += GTK) {
        #pragma unroll
        for (int i = 0; i < 4; ++i) {
            int idx = tid + i * 256;          // 0..1023 over 64x16 A tile
            int m = idx / GTK;
            int k = idx % GTK;
            int gm = bm + m;
            As[k][m] = (gm < M) ? A[(size_t)gm * K + k0 + k] : 0.f;
        }
        #pragma unroll
        for (int i = 0; i < 4; ++i) {
            int idx = tid + i * 256;          // 0..1023 over 16x64 B tile
            int k = idx / GTN;
            int n = idx % GTN;
            Bs[k][n] = W[(size_t)(k0 + k) * Nc + bn + n];
        }
        __syncthreads();
        #pragma unroll
        for (int k = 0; k < GTK; ++k) {
            float av[4], bv[4];
            #pragma unroll
            for (int i = 0; i < 4; ++i) av[i] = As[k][ty * 4 + i];
            #pragma unroll
            for (int j = 0; j < 4; ++j) bv[j] = Bs[k][tx * 4 + j];
            #pragma unroll
            for (int i = 0; i < 4; ++i)
                #pragma unroll
                for (int j = 0; j < 4; ++j) accv[i][j] += av[i] * bv[j];
        }
        __syncthreads();
    }
    #pragma unroll
    for (int i = 0; i < 4; ++i) {
        int gm = bm + ty * 4 + i;
        if (gm >= M) continue;
        #pragma unroll
        for (int j = 0; j < 4; ++j)
            Cb[(size_t)gm * Nc + bn + tx * 4 + j] = accv[i][j];
    }
}

// ---------------- GATv2 edge phase ----------------
// One block per dst node, 4 waves. ONE WAVE PER EDGE: lane holds 4 channels
// (float4), head h = lanes 16h..16h+15, score reduce = 4 shuffles within 16
// lanes. Waves split the edge list 4-way; online-softmax states merged via LDS.

__global__ __launch_bounds__(256) void gat_kernel(const float4* __restrict__ XL4,
                                                  const float4* __restrict__ XR4,
                                                  const int* __restrict__ row_start,
                                                  const int* __restrict__ colx,
                                                  const float4* __restrict__ att4,
                                                  const float* __restrict__ bias,
                                                  float* __restrict__ Hout,
                                                  int relu_flag) {
    int node = blockIdx.x;
    int tid = threadIdx.x;
    int wave = tid >> 6;
    int lane = tid & 63;
    float4 xr = XR4[(size_t)node * 64 + lane];
    float4 a  = att4[lane];
    int e0 = row_start[node], e1 = row_start[node + 1];
    float m = -1e30f, l = 0.f;
    float4 acc = make_float4(0.f, 0.f, 0.f, 0.f);
    for (int e = e0 + wave; e < e1; e += 4) {
        int s = colx[e];
        float4 v = XL4[(size_t)s * 64 + lane];
        float tx = v.x + xr.x; tx = (tx > 0.f) ? tx : NEG_SLOPE * tx;
        float ty = v.y + xr.y; ty = (ty > 0.f) ? ty : NEG_SLOPE * ty;
        float tz = v.z + xr.z; tz = (tz > 0.f) ? tz : NEG_SLOPE * tz;
        float tw = v.w + xr.w; tw = (tw > 0.f) ? tw : NEG_SLOPE * tw;
        float p = a.x * tx + a.y * ty + a.z * tz + a.w * tw;
        p += __shfl_xor(p, 1, 64);
        p += __shfl_xor(p, 2, 64);
        p += __shfl_xor(p, 4, 64);
        p += __shfl_xor(p, 8, 64);       // per-head score in all 16 lanes
        float mn = fmaxf(m, p);
        float scale = __expf(m - mn);
        float pe = __expf(p - mn);
        l = l * scale + pe;
        acc.x = acc.x * scale + pe * v.x;
        acc.y = acc.y * scale + pe * v.y;
        acc.z = acc.z * scale + pe * v.z;
        acc.w = acc.w * scale + pe * v.w;
        m = mn;
    }
    // merge the 4 waves' online-softmax states
    __shared__ float sm[4][4];       // [wave][head]
    __shared__ float sl[4][4];
    __shared__ float sacc[4][HC];
    int head = lane >> 4;
    if ((lane & 15) == 0) { sm[wave][head] = m; sl[wave][head] = l; }
    *(float4*)&sacc[wave][lane * 4] = acc;
    __syncthreads();
    int ch = tid;                    // output channel
    int h = ch >> 6;
    float mm = fmaxf(fmaxf(sm[0][h], sm[1][h]), fmaxf(sm[2][h], sm[3][h]));
    float L = 0.f, A = 0.f;
    #pragma unroll
    for (int w = 0; w < 4; ++w) {
        float sc = __expf(sm[w][h] - mm);   // 0 for empty waves (m=-1e30)
        L += sl[w][h] * sc;
        A += sacc[w][ch] * sc;
    }
    float o = A / L + bias[ch];
    if (relu_flag) o = fmaxf(o, 0.f);
    Hout[(size_t)node * HC + ch] = o;
}

// ---------------- pooling + FC ----------------

__global__ void zero_f(float* p, int n) {
    int i = blockIdx.x * blockDim.x + threadIdx.x;
    if (i < n) p[i] = 0.f;
}

__global__ __launch_bounds__(256) void colsum_kernel(const float* __restrict__ Hmat,
                                                     float* __restrict__ g, int n) {
    int ch = threadIdx.x;
    float s = 0.f;
    for (int r = blockIdx.x; r < n; r += gridDim.x)
        s += Hmat[(size_t)r * HC + ch];
    atomicAdd(&g[ch], s);
}

__global__ __launch_bounds__(256) void fc_kernel(const float* __restrict__ g,
                                                 const float* __restrict__ Wfc,
                                                 const float* __restrict__ bfc,
                                                 float* __restrict__ out, float invN) {
    int t = threadIdx.x;
    float gv = g[t] * invN;
    float p0 = gv * Wfc[2 * t];
    float p1 = gv * Wfc[2 * t + 1];
    #pragma unroll
    for (int off = 32; off > 0; off >>= 1) {
        p0 += __shfl_xor(p0, off, 64);
        p1 += __shfl_xor(p1, off, 64);
    }
    __shared__ float s0[4], s1[4];
    if ((t & 63) == 0) { s0[t >> 6] = p0; s1[t >> 6] = p1; }
    __syncthreads();
    if (t == 0) {
        out[0] = s0[0] + s0[1] + s0[2] + s0[3] + bfc[0];
        out[1] = s1[0] + s1[1] + s1[2] + s1[3] + bfc[1];
    }
}

// ---------------- launch ----------------

extern "C" void kernel_launch(void* const* d_in, const int* in_sizes, int n_in,
                              void* d_out, int out_size, void* d_ws, size_t ws_size,
                              hipStream_t stream) {
    const float* x    = (const float*)d_in[0];
    const int*   eidx = (const int*)d_in[1];   // (2,E) row-major: [src | dst]
    const float* Wl1  = (const float*)d_in[2];
    const float* Wr1  = (const float*)d_in[3];
    const float* att1 = (const float*)d_in[4];
    const float* b1   = (const float*)d_in[5];
    const float* Wl2  = (const float*)d_in[6];
    const float* Wr2  = (const float*)d_in[7];
    const float* att2 = (const float*)d_in[8];
    const float* b2   = (const float*)d_in[9];
    const float* Wfc  = (const float*)d_in[10];
    const float* bfc  = (const float*)d_in[11];
    float* out = (float*)d_out;

    const int* srcv = eidx;
    const int* dstv = eidx + Ee;

    // workspace layout (~63 MB)
    size_t NHC = (size_t)Nn * HC;
    float* XL = (float*)d_ws;
    float* XR = XL + NHC;
    float* Hb = XR + NHC;
    float* g  = Hb + NHC;
    int* deg       = (int*)(g + HC);
    int* row_start = deg + Nn;
    int* cursor    = row_start + (Nn + 1);
    int* colx      = cursor + Nn;              // Ee + Nn entries
    int* bsum      = colx + (Ee + Nn);
    int* boff      = bsum + 128;               // NB+1 entries

    const int NB = (Nn + 255) / 256;           // 79

    // CSR build
    init_deg<<<(Nn + 255) / 256, 256, 0, stream>>>(deg, Nn);
    hist_kernel<<<(Ee + 255) / 256, 256, 0, stream>>>(dstv, Ee, deg);
    scan1<<<NB, 256, 0, stream>>>(deg, row_start, bsum, Nn);
    scan2<<<1, 64, 0, stream>>>(bsum, boff, NB);
    scan_add<<<(Nn + 256) / 256, 256, 0, stream>>>(row_start, cursor, boff, Nn, NB);
    scatter_kernel<<<(Ee + Nn + 255) / 256, 256, 0, stream>>>(srcv, dstv, Ee, Nn, cursor, colx);

    dim3 ggrid(HC / GTN, (Nn + GTM - 1) / GTM);

    // layer 1
    gemm_kernel<<<ggrid, 256, 0, stream>>>(x, Wl1, XL, Nn, INF_, HC);
    gemm_kernel<<<ggrid, 256, 0, stream>>>(x, Wr1, XR, Nn, INF_, HC);
    gat_kernel<<<Nn, 256, 0, stream>>>((const float4*)XL, (const float4*)XR,
                                       row_start, colx, (const float4*)att1, b1, Hb, 1);

    // layer 2
    gemm_kernel<<<ggrid, 256, 0, stream>>>(Hb, Wl2, XL, Nn, HC, HC);
    gemm_kernel<<<ggrid, 256, 0, stream>>>(Hb, Wr2, XR, Nn, HC, HC);
    gat_kernel<<<Nn, 256, 0, stream>>>((const float4*)XL, (const float4*)XR,
                                       row_start, colx, (const float4*)att2, b2, Hb, 1);

    // pool + fc
    zero_f<<<1, 256, 0, stream>>>(g, HC);
    colsum_kernel<<<256, 256, 0, stream>>>(Hb, g, Nn);
    fc_kernel<<<1, 256, 0, stream>>>(g, Wfc, bfc, out, 1.0f / Nn);
}

// Round 4
// 439.987 us; speedup vs baseline: 1.7656x; 1.1634x over previous
//
#include <hip/hip_runtime.h>
#include <hip/hip_bf16.h>
#include <math.h>

#define Nn 20000
#define Ee 320000
#define INF_ 256
#define Hh 4
#define Cc 64
#define HC 256
#define NEG_SLOPE 0.2f

using frag16 = __attribute__((ext_vector_type(8))) short;   // 8 bf16 (4 VGPRs)
using f32x4  = __attribute__((ext_vector_type(4))) float;

// ---------------- CSR build ----------------

__global__ void init_deg(int* deg, int n) {
    int i = blockIdx.x * blockDim.x + threadIdx.x;
    if (i < n) deg[i] = 1;  // self-loop pre-counted
}

__global__ void hist_kernel(const int* __restrict__ dst, int ne, int* deg) {
    int e = blockIdx.x * blockDim.x + threadIdx.x;
    if (e < ne) atomicAdd(&deg[dst[e]], 1);
}

// hierarchical scan, phase 1: per-block (256 elems) exclusive scan + block sum
__global__ __launch_bounds__(256) void scan1(const int* __restrict__ deg,
                                             int* __restrict__ excl,
                                             int* __restrict__ bsum, int n) {
    int tid = threadIdx.x;
    int gid = blockIdx.x * 256 + tid;
    int lane = tid & 63;
    int v = (gid < n) ? deg[gid] : 0;
    int x = v;
    #pragma unroll
    for (int off = 1; off < 64; off <<= 1) {
        int y = __shfl_up(x, off, 64);
        if (lane >= off) x += y;
    }
    __shared__ int wsum[4];
    if (lane == 63) wsum[tid >> 6] = x;
    __syncthreads();
    int wadd = 0;
    for (int w = 0; w < (tid >> 6); ++w) wadd += wsum[w];
    int incl = x + wadd;
    if (gid < n) excl[gid] = incl - v;
    if (tid == 255) bsum[blockIdx.x] = incl;
}

// phase 2: single-wave scan over block sums (nb ~ 79 -> 2 iters)
__global__ void scan2(const int* __restrict__ bsum, int* __restrict__ boff, int nb) {
    int lane = threadIdx.x;
    int carry = 0;
    for (int base = 0; base < nb; base += 64) {
        int i = base + lane;
        int v = (i < nb) ? bsum[i] : 0;
        int x = v;
        #pragma unroll
        for (int off = 1; off < 64; off <<= 1) {
            int y = __shfl_up(x, off, 64);
            if (lane >= off) x += y;
        }
        if (i < nb) boff[i] = carry + x - v;
        carry += __shfl(x, 63, 64);
    }
    if (lane == 0) boff[nb] = carry;
}

// phase 3: add block offsets, produce row_start + cursor (+ total at [n])
__global__ void scan_add(int* __restrict__ row_start, int* __restrict__ cursor,
                         const int* __restrict__ boff, int n, int nb) {
    int gid = blockIdx.x * blockDim.x + threadIdx.x;
    if (gid < n) {
        int v = row_start[gid] + boff[gid >> 8];
        row_start[gid] = v;
        cursor[gid] = v;
    }
    if (gid == n) row_start[n] = boff[nb];
}

__global__ void scatter_kernel(const int* __restrict__ src, const int* __restrict__ dst,
                               int ne, int n, int* cursor, int* colx) {
    int e = blockIdx.x * blockDim.x + threadIdx.x;
    if (e < ne) {
        int d = dst[e];
        int pos = atomicAdd(&cursor[d], 1);
        colx[pos] = src[e];
    } else if (e < ne + n) {
        int node = e - ne;
        int pos = atomicAdd(&cursor[node], 1);
        colx[pos] = node;  // self-loop
    }
}

// ---------------- bf16 split-precision helpers ----------------

__device__ inline unsigned short bf16rn(float f) {
    unsigned u = __float_as_uint(f);
    unsigned r = (u + 0x7FFFu + ((u >> 16) & 1u)) >> 16;   // RTNE, inputs are normal floats
    return (unsigned short)r;
}

__device__ inline void split1(float v, short& h, short& l) {
    unsigned short hh = bf16rn(v);
    float back = __uint_as_float(((unsigned)hh) << 16);
    unsigned short ll = bf16rn(v - back);
    h = (short)hh; l = (short)ll;
}

// fp32 M x 256 -> hi/lo bf16 (same layout), 4 elems/thread
__global__ __launch_bounds__(256) void split_kernel(const float* __restrict__ in,
                                                    short* __restrict__ hi,
                                                    short* __restrict__ lo, int n4) {
    int i = blockIdx.x * blockDim.x + threadIdx.x;
    if (i >= n4) return;
    float4 v = ((const float4*)in)[i];
    short4 h, l;
    split1(v.x, h.x, l.x);
    split1(v.y, h.y, l.y);
    split1(v.z, h.z, l.z);
    split1(v.w, h.w, l.w);
    ((short4*)hi)[i] = h;
    ((short4*)lo)[i] = l;
}

// W (K=256 x N=256 fp32) -> transposed split WT[n][k] hi/lo bf16
__global__ __launch_bounds__(256) void wsplit_kernel(const float* __restrict__ W,
                                                     short* __restrict__ WhT,
                                                     short* __restrict__ WlT) {
    int n = blockIdx.x;     // column of W
    int k = threadIdx.x;
    float v = W[k * 256 + n];
    short h, l;
    split1(v, h, l);
    WhT[n * 256 + k] = h;
    WlT[n * 256 + k] = l;
}

// ---------------- bf16x3 MFMA fused GEMM ----------------
// Computes [XL | XR] = A @ [Wl | Wr] with A ~ Ah+Al, W ~ Wh+Wl (bf16 splits):
// C = Ah*Wh + Al*Wh + Ah*Wl  (dropped Al*Wl term ~2^-18 rel).
// Block: 128 rows x 128 concat-cols, 4 waves; wave: 2 m-tiles x 8 n-tiles of
// 16x16x32 MFMA. B-fragments read straight from L2 (WT is 512 KB, resident).
// A/B frag layout: elem j of lane = [m|n = lane&15][k = (lane>>4)*8 + j].
// C/D layout: col = lane&15, row = (lane>>4)*4 + reg (m89-verified).

__global__ __launch_bounds__(256) void mfma_gemm(const short* __restrict__ Ah,
                                                 const short* __restrict__ Al,
                                                 const short* __restrict__ WhT,
                                                 const short* __restrict__ WlT,
                                                 float* __restrict__ XL,
                                                 float* __restrict__ XR) {
    int tid = threadIdx.x;
    int wave = tid >> 6, lane = tid & 63;
    int quad = lane >> 4, lc = lane & 15;
    int bx = blockIdx.x;                 // 0..3: concat col group (128 cols)
    int bm = blockIdx.y * 128;           // row group
    int row0 = bm + wave * 32;           // wave's 2 m-tiles
    float* Cout = (bx < 2) ? XL : XR;
    int cbase = (bx * 128) & 255;

    int ra0 = row0 + lc;      if (ra0 >= Nn) ra0 = Nn - 1;   // clamp (rows indep.)
    int ra1 = row0 + 16 + lc; if (ra1 >= Nn) ra1 = Nn - 1;

    f32x4 acc[2][8] = {};
    #pragma unroll
    for (int s = 0; s < 8; ++s) {
        int k0 = s * 32 + quad * 8;
        frag16 a0h = *(const frag16*)(Ah + (size_t)ra0 * HC + k0);
        frag16 a0l = *(const frag16*)(Al + (size_t)ra0 * HC + k0);
        frag16 a1h = *(const frag16*)(Ah + (size_t)ra1 * HC + k0);
        frag16 a1l = *(const frag16*)(Al + (size_t)ra1 * HC + k0);
        #pragma unroll
        for (int t = 0; t < 8; ++t) {
            int nc = bx * 128 + t * 16 + lc;     // 0..511 concat col
            frag16 bh = *(const frag16*)(WhT + (size_t)nc * HC + k0);
            frag16 bl = *(const frag16*)(WlT + (size_t)nc * HC + k0);
            acc[0][t] = __builtin_amdgcn_mfma_f32_16x16x32_bf16(a0h, bh, acc[0][t], 0, 0, 0);
            acc[1][t] = __builtin_amdgcn_mfma_f32_16x16x32_bf16(a1h, bh, acc[1][t], 0, 0, 0);
            acc[0][t] = __builtin_amdgcn_mfma_f32_16x16x32_bf16(a0l, bh, acc[0][t], 0, 0, 0);
            acc[1][t] = __builtin_amdgcn_mfma_f32_16x16x32_bf16(a1l, bh, acc[1][t], 0, 0, 0);
            acc[0][t] = __builtin_amdgcn_mfma_f32_16x16x32_bf16(a0h, bl, acc[0][t], 0, 0, 0);
            acc[1][t] = __builtin_amdgcn_mfma_f32_16x16x32_bf16(a1h, bl, acc[1][t], 0, 0, 0);
        }
    }
    #pragma unroll
    for (int mt = 0; mt < 2; ++mt) {
        int rbase = row0 + mt * 16 + quad * 4;
        #pragma unroll
        for (int t = 0; t < 8; ++t) {
            int col = cbase + t * 16 + lc;
            #pragma unroll
            for (int r = 0; r < 4; ++r) {
                int rw = rbase + r;
                if (rw < Nn) Cout[(size_t)rw * HC + col] = acc[mt][t][r];
            }
        }
    }
}

// ---------------- GATv2 edge phase ----------------
// One block per dst node, 4 waves. One wave per edge: lane holds 4 channels
// (float4), head h = lanes 16h..16h+15. Waves split the edge list 4-way;
// online-softmax states merged via LDS.

__global__ __launch_bounds__(256) void gat_kernel(const float4* __restrict__ XL4,
                                                  const float4* __restrict__ XR4,
                                                  const int* __restrict__ row_start,
                                                  const int* __restrict__ colx,
                                                  const float4* __restrict__ att4,
                                                  const float* __restrict__ bias,
                                                  float* __restrict__ Hout,
                                                  int relu_flag) {
    int node = blockIdx.x;
    int tid = threadIdx.x;
    int wave = tid >> 6;
    int lane = tid & 63;
    float4 xr = XR4[(size_t)node * 64 + lane];
    float4 a  = att4[lane];
    int e0 = row_start[node], e1 = row_start[node + 1];
    float m = -1e30f, l = 0.f;
    float4 acc = make_float4(0.f, 0.f, 0.f, 0.f);
    for (int e = e0 + wave; e < e1; e += 4) {
        int s = colx[e];
        float4 v = XL4[(size_t)s * 64 + lane];
        float tx = v.x + xr.x; tx = (tx > 0.f) ? tx : NEG_SLOPE * tx;
        float ty = v.y + xr.y; ty = (ty > 0.f) ? ty : NEG_SLOPE * ty;
        float tz = v.z + xr.z; tz = (tz > 0.f) ? tz : NEG_SLOPE * tz;
        float tw = v.w + xr.w; tw = (tw > 0.f) ? tw : NEG_SLOPE * tw;
        float p = a.x * tx + a.y * ty + a.z * tz + a.w * tw;
        p += __shfl_xor(p, 1, 64);
        p += __shfl_xor(p, 2, 64);
        p += __shfl_xor(p, 4, 64);
        p += __shfl_xor(p, 8, 64);       // per-head score in all 16 lanes
        float mn = fmaxf(m, p);
        float scale = __expf(m - mn);
        float pe = __expf(p - mn);
        l = l * scale + pe;
        acc.x = acc.x * scale + pe * v.x;
        acc.y = acc.y * scale + pe * v.y;
        acc.z = acc.z * scale + pe * v.z;
        acc.w = acc.w * scale + pe * v.w;
        m = mn;
    }
    // merge the 4 waves' online-softmax states
    __shared__ float sm[4][4];       // [wave][head]
    __shared__ float sl[4][4];
    __shared__ float sacc[4][HC];
    int head = lane >> 4;
    if ((lane & 15) == 0) { sm[wave][head] = m; sl[wave][head] = l; }
    *(float4*)&sacc[wave][lane * 4] = acc;
    __syncthreads();
    int ch = tid;                    // output channel
    int h = ch >> 6;
    float mm = fmaxf(fmaxf(sm[0][h], sm[1][h]), fmaxf(sm[2][h], sm[3][h]));
    float L = 0.f, A = 0.f;
    #pragma unroll
    for (int w = 0; w < 4; ++w) {
        float sc = __expf(sm[w][h] - mm);   // 0 for empty waves (m=-1e30)
        L += sl[w][h] * sc;
        A += sacc[w][ch] * sc;
    }
    float o = A / L + bias[ch];
    if (relu_flag) o = fmaxf(o, 0.f);
    Hout[(size_t)node * HC + ch] = o;
}

// ---------------- pooling + FC ----------------

__global__ void zero_f(float* p, int n) {
    int i = blockIdx.x * blockDim.x + threadIdx.x;
    if (i < n) p[i] = 0.f;
}

__global__ __launch_bounds__(256) void colsum_kernel(const float* __restrict__ Hmat,
                                                     float* __restrict__ g, int n) {
    int ch = threadIdx.x;
    float s = 0.f;
    for (int r = blockIdx.x; r < n; r += gridDim.x)
        s += Hmat[(size_t)r * HC + ch];
    atomicAdd(&g[ch], s);
}

__global__ __launch_bounds__(256) void fc_kernel(const float* __restrict__ g,
                                                 const float* __restrict__ Wfc,
                                                 const float* __restrict__ bfc,
                                                 float* __restrict__ out, float invN) {
    int t = threadIdx.x;
    float gv = g[t] * invN;
    float p0 = gv * Wfc[2 * t];
    float p1 = gv * Wfc[2 * t + 1];
    #pragma unroll
    for (int off = 32; off > 0; off >>= 1) {
        p0 += __shfl_xor(p0, off, 64);
        p1 += __shfl_xor(p1, off, 64);
    }
    __shared__ float s0[4], s1[4];
    if ((t & 63) == 0) { s0[t >> 6] = p0; s1[t >> 6] = p1; }
    __syncthreads();
    if (t == 0) {
        out[0] = s0[0] + s0[1] + s0[2] + s0[3] + bfc[0];
        out[1] = s1[0] + s1[1] + s1[2] + s1[3] + bfc[1];
    }
}

// ---------------- launch ----------------

extern "C" void kernel_launch(void* const* d_in, const int* in_sizes, int n_in,
                              void* d_out, int out_size, void* d_ws, size_t ws_size,
                              hipStream_t stream) {
    const float* x    = (const float*)d_in[0];
    const int*   eidx = (const int*)d_in[1];   // (2,E) row-major: [src | dst]
    const float* Wl1  = (const float*)d_in[2];
    const float* Wr1  = (const float*)d_in[3];
    const float* att1 = (const float*)d_in[4];
    const float* b1   = (const float*)d_in[5];
    const float* Wl2  = (const float*)d_in[6];
    const float* Wr2  = (const float*)d_in[7];
    const float* att2 = (const float*)d_in[8];
    const float* b2   = (const float*)d_in[9];
    const float* Wfc  = (const float*)d_in[10];
    const float* bfc  = (const float*)d_in[11];
    float* out = (float*)d_out;

    const int* srcv = eidx;
    const int* dstv = eidx + Ee;

    // workspace layout (~84 MB)
    size_t NHC = (size_t)Nn * HC;
    float* XL = (float*)d_ws;
    float* XR = XL + NHC;
    float* Hb = XR + NHC;
    float* g  = Hb + NHC;
    short* Ah  = (short*)(g + HC);
    short* Al  = Ah + NHC;
    short* WhT = Al + NHC;                     // 512*256 concat [Wl|Wr]^T
    short* WlT = WhT + 512 * 256;
    int* deg       = (int*)(WlT + 512 * 256);
    int* row_start = deg + Nn;
    int* cursor    = row_start + (Nn + 1);
    int* colx      = cursor + Nn;              // Ee + Nn entries
    int* bsum      = colx + (Ee + Nn);
    int* boff      = bsum + 128;               // NB+1 entries

    const int NB = (Nn + 255) / 256;           // 79
    const int N4 = (int)(NHC / 4);

    // CSR build
    init_deg<<<(Nn + 255) / 256, 256, 0, stream>>>(deg, Nn);
    hist_kernel<<<(Ee + 255) / 256, 256, 0, stream>>>(dstv, Ee, deg);
    scan1<<<NB, 256, 0, stream>>>(deg, row_start, bsum, Nn);
    scan2<<<1, 64, 0, stream>>>(bsum, boff, NB);
    scan_add<<<(Nn + 256) / 256, 256, 0, stream>>>(row_start, cursor, boff, Nn, NB);
    scatter_kernel<<<(Ee + Nn + 255) / 256, 256, 0, stream>>>(srcv, dstv, Ee, Nn, cursor, colx);

    dim3 ggrid(4, (Nn + 127) / 128);           // 4 x 157

    // layer 1
    split_kernel<<<(N4 + 255) / 256, 256, 0, stream>>>(x, Ah, Al, N4);
    wsplit_kernel<<<256, 256, 0, stream>>>(Wl1, WhT, WlT);
    wsplit_kernel<<<256, 256, 0, stream>>>(Wr1, WhT + 256 * 256, WlT + 256 * 256);
    mfma_gemm<<<ggrid, 256, 0, stream>>>(Ah, Al, WhT, WlT, XL, XR);
    gat_kernel<<<Nn, 256, 0, stream>>>((const float4*)XL, (const float4*)XR,
                                       row_start, colx, (const float4*)att1, b1, Hb, 1);

    // layer 2
    split_kernel<<<(N4 + 255) / 256, 256, 0, stream>>>(Hb, Ah, Al, N4);
    wsplit_kernel<<<256, 256, 0, stream>>>(Wl2, WhT, WlT);
    wsplit_kernel<<<256, 256, 0, stream>>>(Wr2, WhT + 256 * 256, WlT + 256 * 256);
    mfma_gemm<<<ggrid, 256, 0, stream>>>(Ah, Al, WhT, WlT, XL, XR);
    gat_kernel<<<Nn, 256, 0, stream>>>((const float4*)XL, (const float4*)XR,
                                       row_start, colx, (const float4*)att2, b2, Hb, 1);

    // pool + fc
    zero_f<<<1, 256, 0, stream>>>(g, HC);
    colsum_kernel<<<256, 256, 0, stream>>>(Hb, g, Nn);
    fc_kernel<<<1, 256, 0, stream>>>(g, Wfc, bfc, out, 1.0f / Nn);
}

// Round 5
// 346.011 us; speedup vs baseline: 2.2451x; 1.2716x over previous
//
#include <hip/hip_runtime.h>
#include <hip/hip_bf16.h>
#include <math.h>

#define Nn 20000
#define Ee 320000
#define INF_ 256
#define Hh 4
#define Cc 64
#define HC 256
#define NEG_SLOPE 0.2f

using frag16 = __attribute__((ext_vector_type(8))) short;   // 8 bf16 (4 VGPRs)
using f32x4  = __attribute__((ext_vector_type(4))) float;

// async global->LDS 16B per lane; LDS dest = wave-uniform base + lane*16
__device__ __forceinline__ void async16(const void* g, void* l) {
    __builtin_amdgcn_global_load_lds(
        (const __attribute__((address_space(1))) unsigned int*)g,
        (__attribute__((address_space(3))) unsigned int*)l,
        16, 0, 0);
}

// ---------------- CSR build ----------------

__global__ void init_deg(int* deg, int n) {
    int i = blockIdx.x * blockDim.x + threadIdx.x;
    if (i < n) deg[i] = 1;  // self-loop pre-counted
}

__global__ void hist_kernel(const int* __restrict__ dst, int ne, int* deg) {
    int e = blockIdx.x * blockDim.x + threadIdx.x;
    if (e < ne) atomicAdd(&deg[dst[e]], 1);
}

// hierarchical scan, phase 1: per-block (256 elems) exclusive scan + block sum
__global__ __launch_bounds__(256) void scan1(const int* __restrict__ deg,
                                             int* __restrict__ excl,
                                             int* __restrict__ bsum, int n) {
    int tid = threadIdx.x;
    int gid = blockIdx.x * 256 + tid;
    int lane = tid & 63;
    int v = (gid < n) ? deg[gid] : 0;
    int x = v;
    #pragma unroll
    for (int off = 1; off < 64; off <<= 1) {
        int y = __shfl_up(x, off, 64);
        if (lane >= off) x += y;
    }
    __shared__ int wsum[4];
    if (lane == 63) wsum[tid >> 6] = x;
    __syncthreads();
    int wadd = 0;
    for (int w = 0; w < (tid >> 6); ++w) wadd += wsum[w];
    int incl = x + wadd;
    if (gid < n) excl[gid] = incl - v;
    if (tid == 255) bsum[blockIdx.x] = incl;
}

// phase 2: single-wave scan over block sums (nb ~ 79 -> 2 iters)
__global__ void scan2(const int* __restrict__ bsum, int* __restrict__ boff, int nb) {
    int lane = threadIdx.x;
    int carry = 0;
    for (int base = 0; base < nb; base += 64) {
        int i = base + lane;
        int v = (i < nb) ? bsum[i] : 0;
        int x = v;
        #pragma unroll
        for (int off = 1; off < 64; off <<= 1) {
            int y = __shfl_up(x, off, 64);
            if (lane >= off) x += y;
        }
        if (i < nb) boff[i] = carry + x - v;
        carry += __shfl(x, 63, 64);
    }
    if (lane == 0) boff[nb] = carry;
}

// phase 3: add block offsets, produce row_start + cursor (+ total at [n])
__global__ void scan_add(int* __restrict__ row_start, int* __restrict__ cursor,
                         const int* __restrict__ boff, int n, int nb) {
    int gid = blockIdx.x * blockDim.x + threadIdx.x;
    if (gid < n) {
        int v = row_start[gid] + boff[gid >> 8];
        row_start[gid] = v;
        cursor[gid] = v;
    }
    if (gid == n) row_start[n] = boff[nb];
}

__global__ void scatter_kernel(const int* __restrict__ src, const int* __restrict__ dst,
                               int ne, int n, int* cursor, int* colx) {
    int e = blockIdx.x * blockDim.x + threadIdx.x;
    if (e < ne) {
        int d = dst[e];
        int pos = atomicAdd(&cursor[d], 1);
        colx[pos] = src[e];
    } else if (e < ne + n) {
        int node = e - ne;
        int pos = atomicAdd(&cursor[node], 1);
        colx[pos] = node;  // self-loop
    }
}

// ---------------- bf16 split-precision helpers ----------------

__device__ inline unsigned short bf16rn(float f) {
    unsigned u = __float_as_uint(f);
    unsigned r = (u + 0x7FFFu + ((u >> 16) & 1u)) >> 16;   // RTNE
    return (unsigned short)r;
}

__device__ inline void split1(float v, short& h, short& l) {
    unsigned short hh = bf16rn(v);
    float back = __uint_as_float(((unsigned)hh) << 16);
    unsigned short ll = bf16rn(v - back);
    h = (short)hh; l = (short)ll;
}

// fp32 M x 256 -> hi/lo bf16 (same layout), 4 elems/thread
__global__ __launch_bounds__(256) void split_kernel(const float* __restrict__ in,
                                                    short* __restrict__ hi,
                                                    short* __restrict__ lo, int n4) {
    int i = blockIdx.x * blockDim.x + threadIdx.x;
    if (i >= n4) return;
    float4 v = ((const float4*)in)[i];
    short4 h, l;
    split1(v.x, h.x, l.x);
    split1(v.y, h.y, l.y);
    split1(v.z, h.z, l.z);
    split1(v.w, h.w, l.w);
    ((short4*)hi)[i] = h;
    ((short4*)lo)[i] = l;
}

// W (K=256 x N=256 fp32) -> transposed split WT[n][k] hi/lo bf16
__global__ __launch_bounds__(256) void wsplit_kernel(const float* __restrict__ W,
                                                     short* __restrict__ WhT,
                                                     short* __restrict__ WlT) {
    int n = blockIdx.x;     // column of W
    int k = threadIdx.x;
    float v = W[k * 256 + n];
    short h, l;
    split1(v, h, l);
    WhT[n * 256 + k] = h;
    WlT[n * 256 + k] = l;
}

// ---------------- bf16x3 MFMA fused GEMM, LDS-staged (m97 pattern) ----------
// [XL | XR] = A @ [Wl | Wr],  C = Ah*Wh + Al*Wh + Ah*Wl (bf16x3 split).
// Block: 128 rows x 128 concat-cols, 4 waves. K staged in BK=32 chunks via
// global_load_lds width=16 into 32 KB LDS (Ah/Al/Bh/Bl tiles, [r][k] k-major,
// no padding -- required by the wave-uniform-base+lane*16 LDS write rule).
// Fragments read as ds_read_b128. Frag k = quad*8+j; C/D: col=lane&15,
// row=quad*4+reg (m89-verified).

#define BK 32

__global__ __launch_bounds__(256) void mfma_gemm(const short* __restrict__ Ah,
                                                 const short* __restrict__ Al,
                                                 const short* __restrict__ WhT,
                                                 const short* __restrict__ WlT,
                                                 float* __restrict__ XL,
                                                 float* __restrict__ XR) {
    __shared__ short As_h[128 * BK];
    __shared__ short As_l[128 * BK];
    __shared__ short Bs_h[128 * BK];
    __shared__ short Bs_l[128 * BK];
    int tid = threadIdx.x;
    int wave = tid >> 6, lane = tid & 63;
    int quad = lane >> 4, lc = lane & 15;
    int bx = blockIdx.x;                 // 0..3: concat col group (128 cols)
    int bm = blockIdx.y * 128;           // row group
    float* Cout = (bx < 2) ? XL : XR;
    int cbase = (bx * 128) & 255;

    // staging coords: wave w stages rows [w*32, w*32+32) of each tile;
    // lane i covers row w*32 + i/4, 16B k-slice (i%4)*8 halves.
    int sr0 = wave * 32 + (lane >> 2);   // segment j = wave*2
    int sr1 = sr0 + 16;                  // segment j = wave*2+1
    int koff = (lane & 3) * 8;
    int ga0 = bm + sr0; if (ga0 >= Nn) ga0 = Nn - 1;   // clamp: rows independent
    int ga1 = bm + sr1; if (ga1 >= Nn) ga1 = Nn - 1;
    int gb0 = bx * 128 + sr0;            // B col (< 512 always)
    int gb1 = bx * 128 + sr1;
    int j0 = wave * 2, j1 = j0 + 1;

    f32x4 acc[2][8] = {};
    for (int c = 0; c < 8; ++c) {
        int k0 = c * BK;
        async16(Ah  + (size_t)ga0 * HC + k0 + koff, &As_h[j0 * 512]);
        async16(Ah  + (size_t)ga1 * HC + k0 + koff, &As_h[j1 * 512]);
        async16(Al  + (size_t)ga0 * HC + k0 + koff, &As_l[j0 * 512]);
        async16(Al  + (size_t)ga1 * HC + k0 + koff, &As_l[j1 * 512]);
        async16(WhT + (size_t)gb0 * HC + k0 + koff, &Bs_h[j0 * 512]);
        async16(WhT + (size_t)gb1 * HC + k0 + koff, &Bs_h[j1 * 512]);
        async16(WlT + (size_t)gb0 * HC + k0 + koff, &Bs_l[j0 * 512]);
        async16(WlT + (size_t)gb1 * HC + k0 + koff, &Bs_l[j1 * 512]);
        __syncthreads();                 // drains vmcnt (global_load_lds) too

        frag16 a0h = *(const frag16*)&As_h[(wave * 32 + lc) * BK + quad * 8];
        frag16 a1h = *(const frag16*)&As_h[(wave * 32 + 16 + lc) * BK + quad * 8];
        frag16 a0l = *(const frag16*)&As_l[(wave * 32 + lc) * BK + quad * 8];
        frag16 a1l = *(const frag16*)&As_l[(wave * 32 + 16 + lc) * BK + quad * 8];
        #pragma unroll
        for (int t = 0; t < 8; ++t) {
            frag16 bh = *(const frag16*)&Bs_h[(t * 16 + lc) * BK + quad * 8];
            frag16 bl = *(const frag16*)&Bs_l[(t * 16 + lc) * BK + quad * 8];
            acc[0][t] = __builtin_amdgcn_mfma_f32_16x16x32_bf16(a0h, bh, acc[0][t], 0, 0, 0);
            acc[1][t] = __builtin_amdgcn_mfma_f32_16x16x32_bf16(a1h, bh, acc[1][t], 0, 0, 0);
            acc[0][t] = __builtin_amdgcn_mfma_f32_16x16x32_bf16(a0l, bh, acc[0][t], 0, 0, 0);
            acc[1][t] = __builtin_amdgcn_mfma_f32_16x16x32_bf16(a1l, bh, acc[1][t], 0, 0, 0);
            acc[0][t] = __builtin_amdgcn_mfma_f32_16x16x32_bf16(a0h, bl, acc[0][t], 0, 0, 0);
            acc[1][t] = __builtin_amdgcn_mfma_f32_16x16x32_bf16(a1h, bl, acc[1][t], 0, 0, 0);
        }
        __syncthreads();                 // protect LDS before next-chunk restage
    }
    // wave's rows: wave*32 + mt*16 + quad*4 + r
    #pragma unroll
    for (int mt = 0; mt < 2; ++mt) {
        int rbase = bm + wave * 32 + mt * 16 + quad * 4;
        #pragma unroll
        for (int t = 0; t < 8; ++t) {
            int col = cbase + t * 16 + lc;
            #pragma unroll
            for (int r = 0; r < 4; ++r) {
                int rw = rbase + r;
                if (rw < Nn) Cout[(size_t)rw * HC + col] = acc[mt][t][r];
            }
        }
    }
}

// ---------------- GATv2 edge phase ----------------
// One block per dst node, 4 waves. One wave per edge: lane holds 4 channels
// (float4), head h = lanes 16h..16h+15. Waves split the edge list 4-way;
// online-softmax states merged via LDS.

__global__ __launch_bounds__(256) void gat_kernel(const float4* __restrict__ XL4,
                                                  const float4* __restrict__ XR4,
                                                  const int* __restrict__ row_start,
                                                  const int* __restrict__ colx,
                                                  const float4* __restrict__ att4,
                                                  const float* __restrict__ bias,
                                                  float* __restrict__ Hout,
                                                  int relu_flag) {
    int node = blockIdx.x;
    int tid = threadIdx.x;
    int wave = tid >> 6;
    int lane = tid & 63;
    float4 xr = XR4[(size_t)node * 64 + lane];
    float4 a  = att4[lane];
    int e0 = row_start[node], e1 = row_start[node + 1];
    float m = -1e30f, l = 0.f;
    float4 acc = make_float4(0.f, 0.f, 0.f, 0.f);
    for (int e = e0 + wave; e < e1; e += 4) {
        int s = colx[e];
        float4 v = XL4[(size_t)s * 64 + lane];
        float tx = v.x + xr.x; tx = (tx > 0.f) ? tx : NEG_SLOPE * tx;
        float ty = v.y + xr.y; ty = (ty > 0.f) ? ty : NEG_SLOPE * ty;
        float tz = v.z + xr.z; tz = (tz > 0.f) ? tz : NEG_SLOPE * tz;
        float tw = v.w + xr.w; tw = (tw > 0.f) ? tw : NEG_SLOPE * tw;
        float p = a.x * tx + a.y * ty + a.z * tz + a.w * tw;
        p += __shfl_xor(p, 1, 64);
        p += __shfl_xor(p, 2, 64);
        p += __shfl_xor(p, 4, 64);
        p += __shfl_xor(p, 8, 64);       // per-head score in all 16 lanes
        float mn = fmaxf(m, p);
        float scale = __expf(m - mn);
        float pe = __expf(p - mn);
        l = l * scale + pe;
        acc.x = acc.x * scale + pe * v.x;
        acc.y = acc.y * scale + pe * v.y;
        acc.z = acc.z * scale + pe * v.z;
        acc.w = acc.w * scale + pe * v.w;
        m = mn;
    }
    // merge the 4 waves' online-softmax states
    __shared__ float sm[4][4];       // [wave][head]
    __shared__ float sl[4][4];
    __shared__ float sacc[4][HC];
    int head = lane >> 4;
    if ((lane & 15) == 0) { sm[wave][head] = m; sl[wave][head] = l; }
    *(float4*)&sacc[wave][lane * 4] = acc;
    __syncthreads();
    int ch = tid;                    // output channel
    int h = ch >> 6;
    float mm = fmaxf(fmaxf(sm[0][h], sm[1][h]), fmaxf(sm[2][h], sm[3][h]));
    float L = 0.f, A = 0.f;
    #pragma unroll
    for (int w = 0; w < 4; ++w) {
        float sc = __expf(sm[w][h] - mm);   // 0 for empty waves (m=-1e30)
        L += sl[w][h] * sc;
        A += sacc[w][ch] * sc;
    }
    float o = A / L + bias[ch];
    if (relu_flag) o = fmaxf(o, 0.f);
    Hout[(size_t)node * HC + ch] = o;
}

// ---------------- pooling + FC ----------------

__global__ void zero_f(float* p, int n) {
    int i = blockIdx.x * blockDim.x + threadIdx.x;
    if (i < n) p[i] = 0.f;
}

__global__ __launch_bounds__(256) void colsum_kernel(const float* __restrict__ Hmat,
                                                     float* __restrict__ g, int n) {
    int ch = threadIdx.x;
    float s = 0.f;
    for (int r = blockIdx.x; r < n; r += gridDim.x)
        s += Hmat[(size_t)r * HC + ch];
    atomicAdd(&g[ch], s);
}

__global__ __launch_bounds__(256) void fc_kernel(const float* __restrict__ g,
                                                 const float* __restrict__ Wfc,
                                                 const float* __restrict__ bfc,
                                                 float* __restrict__ out, float invN) {
    int t = threadIdx.x;
    float gv = g[t] * invN;
    float p0 = gv * Wfc[2 * t];
    float p1 = gv * Wfc[2 * t + 1];
    #pragma unroll
    for (int off = 32; off > 0; off >>= 1) {
        p0 += __shfl_xor(p0, off, 64);
        p1 += __shfl_xor(p1, off, 64);
    }
    __shared__ float s0[4], s1[4];
    if ((t & 63) == 0) { s0[t >> 6] = p0; s1[t >> 6] = p1; }
    __syncthreads();
    if (t == 0) {
        out[0] = s0[0] + s0[1] + s0[2] + s0[3] + bfc[0];
        out[1] = s1[0] + s1[1] + s1[2] + s1[3] + bfc[1];
    }
}

// ---------------- launch ----------------

extern "C" void kernel_launch(void* const* d_in, const int* in_sizes, int n_in,
                              void* d_out, int out_size, void* d_ws, size_t ws_size,
                              hipStream_t stream) {
    const float* x    = (const float*)d_in[0];
    const int*   eidx = (const int*)d_in[1];   // (2,E) row-major: [src | dst]
    const float* Wl1  = (const float*)d_in[2];
    const float* Wr1  = (const float*)d_in[3];
    const float* att1 = (const float*)d_in[4];
    const float* b1   = (const float*)d_in[5];
    const float* Wl2  = (const float*)d_in[6];
    const float* Wr2  = (const float*)d_in[7];
    const float* att2 = (const float*)d_in[8];
    const float* b2   = (const float*)d_in[9];
    const float* Wfc  = (const float*)d_in[10];
    const float* bfc  = (const float*)d_in[11];
    float* out = (float*)d_out;

    const int* srcv = eidx;
    const int* dstv = eidx + Ee;

    // workspace layout (~84 MB)
    size_t NHC = (size_t)Nn * HC;
    float* XL = (float*)d_ws;
    float* XR = XL + NHC;
    float* Hb = XR + NHC;
    float* g  = Hb + NHC;
    short* Ah  = (short*)(g + HC);
    short* Al  = Ah + NHC;
    short* WhT = Al + NHC;                     // 512*256 concat [Wl|Wr]^T
    short* WlT = WhT + 512 * 256;
    int* deg       = (int*)(WlT + 512 * 256);
    int* row_start = deg + Nn;
    int* cursor    = row_start + (Nn + 1);
    int* colx      = cursor + Nn;              // Ee + Nn entries
    int* bsum      = colx + (Ee + Nn);
    int* boff      = bsum + 128;               // NB+1 entries

    const int NB = (Nn + 255) / 256;           // 79
    const int N4 = (int)(NHC / 4);

    // CSR build
    init_deg<<<(Nn + 255) / 256, 256, 0, stream>>>(deg, Nn);
    hist_kernel<<<(Ee + 255) / 256, 256, 0, stream>>>(dstv, Ee, deg);
    scan1<<<NB, 256, 0, stream>>>(deg, row_start, bsum, Nn);
    scan2<<<1, 64, 0, stream>>>(bsum, boff, NB);
    scan_add<<<(Nn + 256) / 256, 256, 0, stream>>>(row_start, cursor, boff, Nn, NB);
    scatter_kernel<<<(Ee + Nn + 255) / 256, 256, 0, stream>>>(srcv, dstv, Ee, Nn, cursor, colx);

    dim3 ggrid(4, (Nn + 127) / 128);           // 4 x 157

    // layer 1
    split_kernel<<<(N4 + 255) / 256, 256, 0, stream>>>(x, Ah, Al, N4);
    wsplit_kernel<<<256, 256, 0, stream>>>(Wl1, WhT, WlT);
    wsplit_kernel<<<256, 256, 0, stream>>>(Wr1, WhT + 256 * 256, WlT + 256 * 256);
    mfma_gemm<<<ggrid, 256, 0, stream>>>(Ah, Al, WhT, WlT, XL, XR);
    gat_kernel<<<Nn, 256, 0, stream>>>((const float4*)XL, (const float4*)XR,
                                       row_start, colx, (const float4*)att1, b1, Hb, 1);

    // layer 2
    split_kernel<<<(N4 + 255) / 256, 256, 0, stream>>>(Hb, Ah, Al, N4);
    wsplit_kernel<<<256, 256, 0, stream>>>(Wl2, WhT, WlT);
    wsplit_kernel<<<256, 256, 0, stream>>>(Wr2, WhT + 256 * 256, WlT + 256 * 256);
    mfma_gemm<<<ggrid, 256, 0, stream>>>(Ah, Al, WhT, WlT, XL, XR);
    gat_kernel<<<Nn, 256, 0, stream>>>((const float4*)XL, (const float4*)XR,
                                       row_start, colx, (const float4*)att2, b2, Hb, 1);

    // pool + fc
    zero_f<<<1, 256, 0, stream>>>(g, HC);
    colsum_kernel<<<256, 256, 0, stream>>>(Hb, g, Nn);
    fc_kernel<<<1, 256, 0, stream>>>(g, Wfc, bfc, out, 1.0f / Nn);
}

// Round 6
// 338.480 us; speedup vs baseline: 2.2951x; 1.0222x over previous
//
#include <hip/hip_runtime.h>
#include <hip/hip_bf16.h>
#include <math.h>

#define Nn 20000
#define Ee 320000
#define INF_ 256
#define Hh 4
#define Cc 64
#define HC 256
#define NEG_SLOPE 0.2f

using frag16 = __attribute__((ext_vector_type(8))) short;   // 8 bf16 (4 VGPRs)
using f32x4  = __attribute__((ext_vector_type(4))) float;

// async global->LDS 16B per lane; LDS dest = wave-uniform base + lane*16
__device__ __forceinline__ void async16(const void* g, void* l) {
    __builtin_amdgcn_global_load_lds(
        (const __attribute__((address_space(1))) unsigned int*)g,
        (__attribute__((address_space(3))) unsigned int*)l,
        16, 0, 0);
}

// ---------------- CSR build ----------------

__global__ void init_deg(int* deg, int n) {
    int i = blockIdx.x * blockDim.x + threadIdx.x;
    if (i < n) deg[i] = 1;  // self-loop pre-counted
}

__global__ void hist_kernel(const int* __restrict__ dst, int ne, int* deg) {
    int e = blockIdx.x * blockDim.x + threadIdx.x;
    if (e < ne) atomicAdd(&deg[dst[e]], 1);
}

// hierarchical scan, phase 1: per-block (256 elems) exclusive scan + block sum
__global__ __launch_bounds__(256) void scan1(const int* __restrict__ deg,
                                             int* __restrict__ excl,
                                             int* __restrict__ bsum, int n) {
    int tid = threadIdx.x;
    int gid = blockIdx.x * 256 + tid;
    int lane = tid & 63;
    int v = (gid < n) ? deg[gid] : 0;
    int x = v;
    #pragma unroll
    for (int off = 1; off < 64; off <<= 1) {
        int y = __shfl_up(x, off, 64);
        if (lane >= off) x += y;
    }
    __shared__ int wsum[4];
    if (lane == 63) wsum[tid >> 6] = x;
    __syncthreads();
    int wadd = 0;
    for (int w = 0; w < (tid >> 6); ++w) wadd += wsum[w];
    int incl = x + wadd;
    if (gid < n) excl[gid] = incl - v;
    if (tid == 255) bsum[blockIdx.x] = incl;
}

// phase 2: single-wave scan over block sums (nb ~ 79 -> 2 iters)
__global__ void scan2(const int* __restrict__ bsum, int* __restrict__ boff, int nb) {
    int lane = threadIdx.x;
    int carry = 0;
    for (int base = 0; base < nb; base += 64) {
        int i = base + lane;
        int v = (i < nb) ? bsum[i] : 0;
        int x = v;
        #pragma unroll
        for (int off = 1; off < 64; off <<= 1) {
            int y = __shfl_up(x, off, 64);
            if (lane >= off) x += y;
        }
        if (i < nb) boff[i] = carry + x - v;
        carry += __shfl(x, 63, 64);
    }
    if (lane == 0) boff[nb] = carry;
}

// phase 3: add block offsets, produce row_start + cursor (+ total at [n])
__global__ void scan_add(int* __restrict__ row_start, int* __restrict__ cursor,
                         const int* __restrict__ boff, int n, int nb) {
    int gid = blockIdx.x * blockDim.x + threadIdx.x;
    if (gid < n) {
        int v = row_start[gid] + boff[gid >> 8];
        row_start[gid] = v;
        cursor[gid] = v;
    }
    if (gid == n) row_start[n] = boff[nb];
}

__global__ void scatter_kernel(const int* __restrict__ src, const int* __restrict__ dst,
                               int ne, int n, int* cursor, int* colx) {
    int e = blockIdx.x * blockDim.x + threadIdx.x;
    if (e < ne) {
        int d = dst[e];
        int pos = atomicAdd(&cursor[d], 1);
        colx[pos] = src[e];
    } else if (e < ne + n) {
        int node = e - ne;
        int pos = atomicAdd(&cursor[node], 1);
        colx[pos] = node;  // self-loop
    }
}

// ---------------- bf16 split-precision helpers ----------------

__device__ inline unsigned short bf16rn(float f) {
    unsigned u = __float_as_uint(f);
    unsigned r = (u + 0x7FFFu + ((u >> 16) & 1u)) >> 16;   // RTNE
    return (unsigned short)r;
}

__device__ inline void split1(float v, short& h, short& l) {
    unsigned short hh = bf16rn(v);
    float back = __uint_as_float(((unsigned)hh) << 16);
    unsigned short ll = bf16rn(v - back);
    h = (short)hh; l = (short)ll;
}

// fp32 M x 256 -> hi/lo bf16 (same layout), 4 elems/thread (layer-1 x only)
__global__ __launch_bounds__(256) void split_kernel(const float* __restrict__ in,
                                                    short* __restrict__ hi,
                                                    short* __restrict__ lo, int n4) {
    int i = blockIdx.x * blockDim.x + threadIdx.x;
    if (i >= n4) return;
    float4 v = ((const float4*)in)[i];
    short4 h, l;
    split1(v.x, h.x, l.x);
    split1(v.y, h.y, l.y);
    split1(v.z, h.z, l.z);
    split1(v.w, h.w, l.w);
    ((short4*)hi)[i] = h;
    ((short4*)lo)[i] = l;
}

// all 4 weight matrices (K=256 x N=256 fp32) -> transposed split, one dispatch.
// blocks 0-255: L1 Wl | 256-511: L1 Wr | 512-767: L2 Wl | 768-1023: L2 Wr
__global__ __launch_bounds__(256) void wsplit_all(const float* __restrict__ Wl1,
                                                  const float* __restrict__ Wr1,
                                                  const float* __restrict__ Wl2,
                                                  const float* __restrict__ Wr2,
                                                  short* __restrict__ WhT1,
                                                  short* __restrict__ WlT1,
                                                  short* __restrict__ WhT2,
                                                  short* __restrict__ WlT2) {
    int b = blockIdx.x;
    int n = b & 255;
    int k = threadIdx.x;
    const float* W = (b < 256) ? Wl1 : (b < 512) ? Wr1 : (b < 768) ? Wl2 : Wr2;
    short* Wh = (b < 512) ? WhT1 : WhT2;
    short* Wl = (b < 512) ? WlT1 : WlT2;
    int col = b & 511;                  // concat col within layer
    float v = W[k * 256 + n];
    short h, l;
    split1(v, h, l);
    Wh[col * 256 + k] = h;
    Wl[col * 256 + k] = l;
}

// ---------------- bf16x3 MFMA fused GEMM, LDS-staged (m97 pattern) ----------
// [XL | XR] = A @ [Wl | Wr],  C = Ah*Wh + Al*Wh + Ah*Wl (bf16x3 split).

#define BK 32

__global__ __launch_bounds__(256) void mfma_gemm(const short* __restrict__ Ah,
                                                 const short* __restrict__ Al,
                                                 const short* __restrict__ WhT,
                                                 const short* __restrict__ WlT,
                                                 float* __restrict__ XL,
                                                 float* __restrict__ XR) {
    __shared__ short As_h[128 * BK];
    __shared__ short As_l[128 * BK];
    __shared__ short Bs_h[128 * BK];
    __shared__ short Bs_l[128 * BK];
    int tid = threadIdx.x;
    int wave = tid >> 6, lane = tid & 63;
    int quad = lane >> 4, lc = lane & 15;
    int bx = blockIdx.x;                 // 0..3: concat col group (128 cols)
    int bm = blockIdx.y * 128;           // row group
    float* Cout = (bx < 2) ? XL : XR;
    int cbase = (bx * 128) & 255;

    int sr0 = wave * 32 + (lane >> 2);
    int sr1 = sr0 + 16;
    int koff = (lane & 3) * 8;
    int ga0 = bm + sr0; if (ga0 >= Nn) ga0 = Nn - 1;
    int ga1 = bm + sr1; if (ga1 >= Nn) ga1 = Nn - 1;
    int gb0 = bx * 128 + sr0;
    int gb1 = bx * 128 + sr1;
    int j0 = wave * 2, j1 = j0 + 1;

    f32x4 acc[2][8] = {};
    for (int c = 0; c < 8; ++c) {
        int k0 = c * BK;
        async16(Ah  + (size_t)ga0 * HC + k0 + koff, &As_h[j0 * 512]);
        async16(Ah  + (size_t)ga1 * HC + k0 + koff, &As_h[j1 * 512]);
        async16(Al  + (size_t)ga0 * HC + k0 + koff, &As_l[j0 * 512]);
        async16(Al  + (size_t)ga1 * HC + k0 + koff, &As_l[j1 * 512]);
        async16(WhT + (size_t)gb0 * HC + k0 + koff, &Bs_h[j0 * 512]);
        async16(WhT + (size_t)gb1 * HC + k0 + koff, &Bs_h[j1 * 512]);
        async16(WlT + (size_t)gb0 * HC + k0 + koff, &Bs_l[j0 * 512]);
        async16(WlT + (size_t)gb1 * HC + k0 + koff, &Bs_l[j1 * 512]);
        __syncthreads();

        frag16 a0h = *(const frag16*)&As_h[(wave * 32 + lc) * BK + quad * 8];
        frag16 a1h = *(const frag16*)&As_h[(wave * 32 + 16 + lc) * BK + quad * 8];
        frag16 a0l = *(const frag16*)&As_l[(wave * 32 + lc) * BK + quad * 8];
        frag16 a1l = *(const frag16*)&As_l[(wave * 32 + 16 + lc) * BK + quad * 8];
        #pragma unroll
        for (int t = 0; t < 8; ++t) {
            frag16 bh = *(const frag16*)&Bs_h[(t * 16 + lc) * BK + quad * 8];
            frag16 bl = *(const frag16*)&Bs_l[(t * 16 + lc) * BK + quad * 8];
            acc[0][t] = __builtin_amdgcn_mfma_f32_16x16x32_bf16(a0h, bh, acc[0][t], 0, 0, 0);
            acc[1][t] = __builtin_amdgcn_mfma_f32_16x16x32_bf16(a1h, bh, acc[1][t], 0, 0, 0);
            acc[0][t] = __builtin_amdgcn_mfma_f32_16x16x32_bf16(a0l, bh, acc[0][t], 0, 0, 0);
            acc[1][t] = __builtin_amdgcn_mfma_f32_16x16x32_bf16(a1l, bh, acc[1][t], 0, 0, 0);
            acc[0][t] = __builtin_amdgcn_mfma_f32_16x16x32_bf16(a0h, bl, acc[0][t], 0, 0, 0);
            acc[1][t] = __builtin_amdgcn_mfma_f32_16x16x32_bf16(a1h, bl, acc[1][t], 0, 0, 0);
        }
        __syncthreads();
    }
    #pragma unroll
    for (int mt = 0; mt < 2; ++mt) {
        int rbase = bm + wave * 32 + mt * 16 + quad * 4;
        #pragma unroll
        for (int t = 0; t < 8; ++t) {
            int col = cbase + t * 16 + lc;
            #pragma unroll
            for (int r = 0; r < 4; ++r) {
                int rw = rbase + r;
                if (rw < Nn) Cout[(size_t)rw * HC + col] = acc[mt][t][r];
            }
        }
    }
}

// ---------------- GATv2 edge phase ----------------
// ONE WAVE PER NODE (4 nodes/block, no inter-wave merge, no barriers).
// Lane holds 4 channels (float4); head h = lanes 16h..16h+15.
// Softmax without max subtraction: scores provably bounded (|score| <~ 21
// by Cauchy-Schwarz, ~8 empirically) << 88 = fp32 exp overflow; softmax is
// shift-invariant so result identical to within fp32 rounding.
// leaky(t) = 0.6t + 0.4|t|  =>  score = sum (0.6a)t + (0.4a)|t|.
// mode 0: write fp32 H (relu). mode 1: write bf16 hi/lo split (relu) -- feeds
// next layer's MFMA GEMM directly, no separate split pass.

__global__ __launch_bounds__(256) void gat_kernel(const float4* __restrict__ XL4,
                                                  const float4* __restrict__ XR4,
                                                  const int* __restrict__ row_start,
                                                  const int* __restrict__ colx,
                                                  const float4* __restrict__ att4,
                                                  const float4* __restrict__ bias4,
                                                  float4* __restrict__ Hout,
                                                  short4* __restrict__ Ahi,
                                                  short4* __restrict__ Alo,
                                                  int mode) {
    int wave = threadIdx.x >> 6, lane = threadIdx.x & 63;
    int node = blockIdx.x * 4 + wave;          // grid = Nn/4 exactly
    float4 xr = XR4[(size_t)node * 64 + lane];
    float4 a  = att4[lane];
    float4 a06 = make_float4(a.x * 0.6f, a.y * 0.6f, a.z * 0.6f, a.w * 0.6f);
    float4 a04 = make_float4(a.x * 0.4f, a.y * 0.4f, a.z * 0.4f, a.w * 0.4f);
    int e0 = row_start[node], e1 = row_start[node + 1];
    float l = 0.f;
    float4 acc = make_float4(0.f, 0.f, 0.f, 0.f);
    for (int e = e0; e < e1; ++e) {
        int s = __builtin_amdgcn_readfirstlane(colx[e]);   // scalar addr path
        float4 v = XL4[(size_t)s * 64 + lane];
        float tx = v.x + xr.x, ty = v.y + xr.y, tz = v.z + xr.z, tw = v.w + xr.w;
        float p = a06.x * tx + a04.x * fabsf(tx);
        p += a06.y * ty + a04.y * fabsf(ty);
        p += a06.z * tz + a04.z * fabsf(tz);
        p += a06.w * tw + a04.w * fabsf(tw);
        p += __shfl_xor(p, 1, 64);
        p += __shfl_xor(p, 2, 64);
        p += __shfl_xor(p, 4, 64);
        p += __shfl_xor(p, 8, 64);             // per-head score in its 16 lanes
        float pe = __expf(p);
        l += pe;
        acc.x += pe * v.x;
        acc.y += pe * v.y;
        acc.z += pe * v.z;
        acc.w += pe * v.w;
    }
    float rl = 1.f / l;
    float4 b = bias4[lane];
    float4 o = make_float4(fmaxf(acc.x * rl + b.x, 0.f),
                           fmaxf(acc.y * rl + b.y, 0.f),
                           fmaxf(acc.z * rl + b.z, 0.f),
                           fmaxf(acc.w * rl + b.w, 0.f));
    size_t oidx = (size_t)node * 64 + lane;
    if (mode) {
        short4 h4, l4;
        split1(o.x, h4.x, l4.x);
        split1(o.y, h4.y, l4.y);
        split1(o.z, h4.z, l4.z);
        split1(o.w, h4.w, l4.w);
        Ahi[oidx] = h4;
        Alo[oidx] = l4;
    } else {
        Hout[oidx] = o;
    }
}

// ---------------- pooling + FC ----------------

__global__ void zero_f(float* p, int n) {
    int i = blockIdx.x * blockDim.x + threadIdx.x;
    if (i < n) p[i] = 0.f;
}

__global__ __launch_bounds__(256) void colsum_kernel(const float* __restrict__ Hmat,
                                                     float* __restrict__ g, int n) {
    int ch = threadIdx.x;
    float s = 0.f;
    for (int r = blockIdx.x; r < n; r += gridDim.x)
        s += Hmat[(size_t)r * HC + ch];
    atomicAdd(&g[ch], s);
}

__global__ __launch_bounds__(256) void fc_kernel(const float* __restrict__ g,
                                                 const float* __restrict__ Wfc,
                                                 const float* __restrict__ bfc,
                                                 float* __restrict__ out, float invN) {
    int t = threadIdx.x;
    float gv = g[t] * invN;
    float p0 = gv * Wfc[2 * t];
    float p1 = gv * Wfc[2 * t + 1];
    #pragma unroll
    for (int off = 32; off > 0; off >>= 1) {
        p0 += __shfl_xor(p0, off, 64);
        p1 += __shfl_xor(p1, off, 64);
    }
    __shared__ float s0[4], s1[4];
    if ((t & 63) == 0) { s0[t >> 6] = p0; s1[t >> 6] = p1; }
    __syncthreads();
    if (t == 0) {
        out[0] = s0[0] + s0[1] + s0[2] + s0[3] + bfc[0];
        out[1] = s1[0] + s1[1] + s1[2] + s1[3] + bfc[1];
    }
}

// ---------------- launch ----------------

extern "C" void kernel_launch(void* const* d_in, const int* in_sizes, int n_in,
                              void* d_out, int out_size, void* d_ws, size_t ws_size,
                              hipStream_t stream) {
    const float* x    = (const float*)d_in[0];
    const int*   eidx = (const int*)d_in[1];   // (2,E) row-major: [src | dst]
    const float* Wl1  = (const float*)d_in[2];
    const float* Wr1  = (const float*)d_in[3];
    const float* att1 = (const float*)d_in[4];
    const float* b1   = (const float*)d_in[5];
    const float* Wl2  = (const float*)d_in[6];
    const float* Wr2  = (const float*)d_in[7];
    const float* att2 = (const float*)d_in[8];
    const float* b2   = (const float*)d_in[9];
    const float* Wfc  = (const float*)d_in[10];
    const float* bfc  = (const float*)d_in[11];
    float* out = (float*)d_out;

    const int* srcv = eidx;
    const int* dstv = eidx + Ee;

    // workspace layout (~85 MB)
    size_t NHC = (size_t)Nn * HC;
    float* XL = (float*)d_ws;
    float* XR = XL + NHC;
    float* Hb = XR + NHC;
    float* g  = Hb + NHC;
    short* Ah   = (short*)(g + HC);
    short* Al   = Ah + NHC;
    short* WhT1 = Al + NHC;                    // 512*256 concat [Wl|Wr]^T per layer
    short* WlT1 = WhT1 + 512 * 256;
    short* WhT2 = WlT1 + 512 * 256;
    short* WlT2 = WhT2 + 512 * 256;
    int* deg       = (int*)(WlT2 + 512 * 256);
    int* row_start = deg + Nn;
    int* cursor    = row_start + (Nn + 1);
    int* colx      = cursor + Nn;              // Ee + Nn entries
    int* bsum      = colx + (Ee + Nn);
    int* boff      = bsum + 128;               // NB+1 entries

    const int NB = (Nn + 255) / 256;           // 79
    const int N4 = (int)(NHC / 4);

    // CSR build
    init_deg<<<(Nn + 255) / 256, 256, 0, stream>>>(deg, Nn);
    hist_kernel<<<(Ee + 255) / 256, 256, 0, stream>>>(dstv, Ee, deg);
    scan1<<<NB, 256, 0, stream>>>(deg, row_start, bsum, Nn);
    scan2<<<1, 64, 0, stream>>>(bsum, boff, NB);
    scan_add<<<(Nn + 256) / 256, 256, 0, stream>>>(row_start, cursor, boff, Nn, NB);
    scatter_kernel<<<(Ee + Nn + 255) / 256, 256, 0, stream>>>(srcv, dstv, Ee, Nn, cursor, colx);

    dim3 ggrid(4, (Nn + 127) / 128);           // 4 x 157

    // weight prep (both layers, one dispatch) + layer-1 input split
    wsplit_all<<<1024, 256, 0, stream>>>(Wl1, Wr1, Wl2, Wr2, WhT1, WlT1, WhT2, WlT2);
    split_kernel<<<(N4 + 255) / 256, 256, 0, stream>>>(x, Ah, Al, N4);

    // layer 1 (gat writes bf16 split directly -> layer-2 GEMM input)
    mfma_gemm<<<ggrid, 256, 0, stream>>>(Ah, Al, WhT1, WlT1, XL, XR);
    gat_kernel<<<Nn / 4, 256, 0, stream>>>((const float4*)XL, (const float4*)XR,
                                           row_start, colx, (const float4*)att1,
                                           (const float4*)b1, (float4*)Hb,
                                           (short4*)Ah, (short4*)Al, 1);

    // layer 2
    mfma_gemm<<<ggrid, 256, 0, stream>>>(Ah, Al, WhT2, WlT2, XL, XR);
    gat_kernel<<<Nn / 4, 256, 0, stream>>>((const float4*)XL, (const float4*)XR,
                                           row_start, colx, (const float4*)att2,
                                           (const float4*)b2, (float4*)Hb,
                                           (short4*)Ah, (short4*)Al, 0);

    // pool + fc
    zero_f<<<1, 256, 0, stream>>>(g, HC);
    colsum_kernel<<<256, 256, 0, stream>>>(Hb, g, Nn);
    fc_kernel<<<1, 256, 0, stream>>>(g, Wfc, bfc, out, 1.0f / Nn);
}

// Round 7
// 296.064 us; speedup vs baseline: 2.6239x; 1.1433x over previous
//
#include <hip/hip_runtime.h>
#include <hip/hip_bf16.h>
#include <math.h>

#define Nn 20000
#define Ee 320000
#define INF_ 256
#define Hh 4
#define Cc 64
#define HC 256
#define NEG_SLOPE 0.2f

using frag16 = __attribute__((ext_vector_type(8))) short;   // 8 bf16 (4 VGPRs)
using f32x4  = __attribute__((ext_vector_type(4))) float;

// async global->LDS 16B per lane; LDS dest = wave-uniform base + lane*16
__device__ __forceinline__ void async16(const void* g, void* l) {
    __builtin_amdgcn_global_load_lds(
        (const __attribute__((address_space(1))) unsigned int*)g,
        (__attribute__((address_space(3))) unsigned int*)l,
        16, 0, 0);
}

// ---------------- CSR build ----------------

__global__ void init_deg(int* deg, int n) {
    int i = blockIdx.x * blockDim.x + threadIdx.x;
    if (i < n) deg[i] = 1;  // self-loop pre-counted
}

__global__ void hist_kernel(const int* __restrict__ dst, int ne, int* deg) {
    int e = blockIdx.x * blockDim.x + threadIdx.x;
    if (e < ne) atomicAdd(&deg[dst[e]], 1);
}

// hierarchical scan, phase 1: per-block (256 elems) exclusive scan + block sum
__global__ __launch_bounds__(256) void scan1(const int* __restrict__ deg,
                                             int* __restrict__ excl,
                                             int* __restrict__ bsum, int n) {
    int tid = threadIdx.x;
    int gid = blockIdx.x * 256 + tid;
    int lane = tid & 63;
    int v = (gid < n) ? deg[gid] : 0;
    int x = v;
    #pragma unroll
    for (int off = 1; off < 64; off <<= 1) {
        int y = __shfl_up(x, off, 64);
        if (lane >= off) x += y;
    }
    __shared__ int wsum[4];
    if (lane == 63) wsum[tid >> 6] = x;
    __syncthreads();
    int wadd = 0;
    for (int w = 0; w < (tid >> 6); ++w) wadd += wsum[w];
    int incl = x + wadd;
    if (gid < n) excl[gid] = incl - v;
    if (tid == 255) bsum[blockIdx.x] = incl;
}

// phase 2: single-wave scan over block sums (nb ~ 79 -> 2 iters)
__global__ void scan2(const int* __restrict__ bsum, int* __restrict__ boff, int nb) {
    int lane = threadIdx.x;
    int carry = 0;
    for (int base = 0; base < nb; base += 64) {
        int i = base + lane;
        int v = (i < nb) ? bsum[i] : 0;
        int x = v;
        #pragma unroll
        for (int off = 1; off < 64; off <<= 1) {
            int y = __shfl_up(x, off, 64);
            if (lane >= off) x += y;
        }
        if (i < nb) boff[i] = carry + x - v;
        carry += __shfl(x, 63, 64);
    }
    if (lane == 0) boff[nb] = carry;
}

// phase 3: add block offsets, produce row_start + cursor (+ total at [n])
__global__ void scan_add(int* __restrict__ row_start, int* __restrict__ cursor,
                         const int* __restrict__ boff, int n, int nb) {
    int gid = blockIdx.x * blockDim.x + threadIdx.x;
    if (gid < n) {
        int v = row_start[gid] + boff[gid >> 8];
        row_start[gid] = v;
        cursor[gid] = v;
    }
    if (gid == n) row_start[n] = boff[nb];
}

__global__ void scatter_kernel(const int* __restrict__ src, const int* __restrict__ dst,
                               int ne, int n, int* cursor, int* colx) {
    int e = blockIdx.x * blockDim.x + threadIdx.x;
    if (e < ne) {
        int d = dst[e];
        int pos = atomicAdd(&cursor[d], 1);
        colx[pos] = src[e];
    } else if (e < ne + n) {
        int node = e - ne;
        int pos = atomicAdd(&cursor[node], 1);
        colx[pos] = node;  // self-loop
    }
}

// ---------------- bf16 split-precision helpers ----------------

__device__ inline unsigned short bf16rn(float f) {
    unsigned u = __float_as_uint(f);
    unsigned r = (u + 0x7FFFu + ((u >> 16) & 1u)) >> 16;   // RTNE
    return (unsigned short)r;
}

__device__ inline void split1(float v, short& h, short& l) {
    unsigned short hh = bf16rn(v);
    float back = __uint_as_float(((unsigned)hh) << 16);
    unsigned short ll = bf16rn(v - back);
    h = (short)hh; l = (short)ll;
}

__device__ __forceinline__ float4 bf4_to_f4(ushort4 u) {
    return make_float4(__uint_as_float((unsigned)u.x << 16),
                       __uint_as_float((unsigned)u.y << 16),
                       __uint_as_float((unsigned)u.z << 16),
                       __uint_as_float((unsigned)u.w << 16));
}

// fp32 M x 256 -> hi/lo bf16 (same layout), 4 elems/thread (layer-1 x only)
__global__ __launch_bounds__(256) void split_kernel(const float* __restrict__ in,
                                                    short* __restrict__ hi,
                                                    short* __restrict__ lo, int n4) {
    int i = blockIdx.x * blockDim.x + threadIdx.x;
    if (i >= n4) return;
    float4 v = ((const float4*)in)[i];
    short4 h, l;
    split1(v.x, h.x, l.x);
    split1(v.y, h.y, l.y);
    split1(v.z, h.z, l.z);
    split1(v.w, h.w, l.w);
    ((short4*)hi)[i] = h;
    ((short4*)lo)[i] = l;
}

// all 4 weight matrices (K=256 x N=256 fp32) -> transposed split, one dispatch.
__global__ __launch_bounds__(256) void wsplit_all(const float* __restrict__ Wl1,
                                                  const float* __restrict__ Wr1,
                                                  const float* __restrict__ Wl2,
                                                  const float* __restrict__ Wr2,
                                                  short* __restrict__ WhT1,
                                                  short* __restrict__ WlT1,
                                                  short* __restrict__ WhT2,
                                                  short* __restrict__ WlT2) {
    int b = blockIdx.x;
    int n = b & 255;
    int k = threadIdx.x;
    const float* W = (b < 256) ? Wl1 : (b < 512) ? Wr1 : (b < 768) ? Wl2 : Wr2;
    short* Wh = (b < 512) ? WhT1 : WhT2;
    short* Wl = (b < 512) ? WlT1 : WlT2;
    int col = b & 511;                  // concat col within layer
    float v = W[k * 256 + n];
    short h, l;
    split1(v, h, l);
    Wh[col * 256 + k] = h;
    Wl[col * 256 + k] = l;
}

// ---------------- bf16x3 MFMA fused GEMM, LDS-staged (m97 pattern) ----------
// [XL | XR] = A @ [Wl | Wr],  C = Ah*Wh + Al*Wh + Ah*Wl (bf16x3 split).
// XL written as bf16-hi only (gat gathers it -- halves beyond-L2 gather
// traffic and working set); XR written fp32 (read once per node, score dst
// side keeps full precision).

#define BK 32

__global__ __launch_bounds__(256) void mfma_gemm(const short* __restrict__ Ah,
                                                 const short* __restrict__ Al,
                                                 const short* __restrict__ WhT,
                                                 const short* __restrict__ WlT,
                                                 unsigned short* __restrict__ XLh,
                                                 float* __restrict__ XR) {
    __shared__ short As_h[128 * BK];
    __shared__ short As_l[128 * BK];
    __shared__ short Bs_h[128 * BK];
    __shared__ short Bs_l[128 * BK];
    int tid = threadIdx.x;
    int wave = tid >> 6, lane = tid & 63;
    int quad = lane >> 4, lc = lane & 15;
    int bx = blockIdx.x;                 // 0..3: concat col group (128 cols)
    int bm = blockIdx.y * 128;           // row group
    int cbase = (bx * 128) & 255;

    int sr0 = wave * 32 + (lane >> 2);
    int sr1 = sr0 + 16;
    int koff = (lane & 3) * 8;
    int ga0 = bm + sr0; if (ga0 >= Nn) ga0 = Nn - 1;
    int ga1 = bm + sr1; if (ga1 >= Nn) ga1 = Nn - 1;
    int gb0 = bx * 128 + sr0;
    int gb1 = bx * 128 + sr1;
    int j0 = wave * 2, j1 = j0 + 1;

    f32x4 acc[2][8] = {};
    for (int c = 0; c < 8; ++c) {
        int k0 = c * BK;
        async16(Ah  + (size_t)ga0 * HC + k0 + koff, &As_h[j0 * 512]);
        async16(Ah  + (size_t)ga1 * HC + k0 + koff, &As_h[j1 * 512]);
        async16(Al  + (size_t)ga0 * HC + k0 + koff, &As_l[j0 * 512]);
        async16(Al  + (size_t)ga1 * HC + k0 + koff, &As_l[j1 * 512]);
        async16(WhT + (size_t)gb0 * HC + k0 + koff, &Bs_h[j0 * 512]);
        async16(WhT + (size_t)gb1 * HC + k0 + koff, &Bs_h[j1 * 512]);
        async16(WlT + (size_t)gb0 * HC + k0 + koff, &Bs_l[j0 * 512]);
        async16(WlT + (size_t)gb1 * HC + k0 + koff, &Bs_l[j1 * 512]);
        __syncthreads();

        frag16 a0h = *(const frag16*)&As_h[(wave * 32 + lc) * BK + quad * 8];
        frag16 a1h = *(const frag16*)&As_h[(wave * 32 + 16 + lc) * BK + quad * 8];
        frag16 a0l = *(const frag16*)&As_l[(wave * 32 + lc) * BK + quad * 8];
        frag16 a1l = *(const frag16*)&As_l[(wave * 32 + 16 + lc) * BK + quad * 8];
        #pragma unroll
        for (int t = 0; t < 8; ++t) {
            frag16 bh = *(const frag16*)&Bs_h[(t * 16 + lc) * BK + quad * 8];
            frag16 bl = *(const frag16*)&Bs_l[(t * 16 + lc) * BK + quad * 8];
            acc[0][t] = __builtin_amdgcn_mfma_f32_16x16x32_bf16(a0h, bh, acc[0][t], 0, 0, 0);
            acc[1][t] = __builtin_amdgcn_mfma_f32_16x16x32_bf16(a1h, bh, acc[1][t], 0, 0, 0);
            acc[0][t] = __builtin_amdgcn_mfma_f32_16x16x32_bf16(a0l, bh, acc[0][t], 0, 0, 0);
            acc[1][t] = __builtin_amdgcn_mfma_f32_16x16x32_bf16(a1l, bh, acc[1][t], 0, 0, 0);
            acc[0][t] = __builtin_amdgcn_mfma_f32_16x16x32_bf16(a0h, bl, acc[0][t], 0, 0, 0);
            acc[1][t] = __builtin_amdgcn_mfma_f32_16x16x32_bf16(a1h, bl, acc[1][t], 0, 0, 0);
        }
        __syncthreads();
    }
    #pragma unroll
    for (int mt = 0; mt < 2; ++mt) {
        int rbase = bm + wave * 32 + mt * 16 + quad * 4;
        #pragma unroll
        for (int t = 0; t < 8; ++t) {
            int col = cbase + t * 16 + lc;
            #pragma unroll
            for (int r = 0; r < 4; ++r) {
                int rw = rbase + r;
                if (rw >= Nn) continue;
                if (bx < 2) XLh[(size_t)rw * HC + col] = bf16rn(acc[mt][t][r]);
                else        XR [(size_t)rw * HC + col] = acc[mt][t][r];
            }
        }
    }
}

// ---------------- GATv2 edge phase ----------------
// One wave per node (4 nodes/block). Lane holds 4 channels; head h = lanes
// 16h..16h+15. XL gathered in bf16 (8 B/lane); XR/bias fp32.
// No-max softmax (scores bounded << 88); leaky(t)=0.6t+0.4|t|.
// 2-way edge unroll w/ independent partials for memory-level parallelism.
// mode 1: also write bf16 hi/lo split of relu(h) for next layer's GEMM.

__device__ __forceinline__ float edge_score(const float4 v, const float4 xr,
                                            const float4 a06, const float4 a04) {
    float tx = v.x + xr.x, ty = v.y + xr.y, tz = v.z + xr.z, tw = v.w + xr.w;
    float p = a06.x * tx + a04.x * fabsf(tx);
    p += a06.y * ty + a04.y * fabsf(ty);
    p += a06.z * tz + a04.z * fabsf(tz);
    p += a06.w * tw + a04.w * fabsf(tw);
    p += __shfl_xor(p, 1, 64);
    p += __shfl_xor(p, 2, 64);
    p += __shfl_xor(p, 4, 64);
    p += __shfl_xor(p, 8, 64);             // per-head score in its 16 lanes
    return p;
}

__global__ __launch_bounds__(256) void gat_kernel(const ushort4* __restrict__ XL4,
                                                  const float4* __restrict__ XR4,
                                                  const int* __restrict__ row_start,
                                                  const int* __restrict__ colx,
                                                  const float4* __restrict__ att4,
                                                  const float4* __restrict__ bias4,
                                                  float4* __restrict__ Hout,
                                                  short4* __restrict__ Ahi,
                                                  short4* __restrict__ Alo,
                                                  int mode) {
    int wave = threadIdx.x >> 6, lane = threadIdx.x & 63;
    int node = blockIdx.x * 4 + wave;          // grid = Nn/4 exactly
    float4 xr = XR4[(size_t)node * 64 + lane];
    float4 a  = att4[lane];
    float4 a06 = make_float4(a.x * 0.6f, a.y * 0.6f, a.z * 0.6f, a.w * 0.6f);
    float4 a04 = make_float4(a.x * 0.4f, a.y * 0.4f, a.z * 0.4f, a.w * 0.4f);
    int e0 = row_start[node], e1 = row_start[node + 1];
    float l0 = 0.f, l1 = 0.f;
    float4 acc0 = make_float4(0.f, 0.f, 0.f, 0.f);
    float4 acc1 = make_float4(0.f, 0.f, 0.f, 0.f);
    int e = e0;
    for (; e + 1 < e1; e += 2) {
        int s0 = __builtin_amdgcn_readfirstlane(colx[e]);
        int s1 = __builtin_amdgcn_readfirstlane(colx[e + 1]);
        ushort4 u0 = XL4[(size_t)s0 * 64 + lane];
        ushort4 u1 = XL4[(size_t)s1 * 64 + lane];
        float4 v0 = bf4_to_f4(u0);
        float4 v1 = bf4_to_f4(u1);
        float pe0 = __expf(edge_score(v0, xr, a06, a04));
        float pe1 = __expf(edge_score(v1, xr, a06, a04));
        l0 += pe0; l1 += pe1;
        acc0.x += pe0 * v0.x; acc0.y += pe0 * v0.y;
        acc0.z += pe0 * v0.z; acc0.w += pe0 * v0.w;
        acc1.x += pe1 * v1.x; acc1.y += pe1 * v1.y;
        acc1.z += pe1 * v1.z; acc1.w += pe1 * v1.w;
    }
    if (e < e1) {
        int s0 = __builtin_amdgcn_readfirstlane(colx[e]);
        float4 v0 = bf4_to_f4(XL4[(size_t)s0 * 64 + lane]);
        float pe0 = __expf(edge_score(v0, xr, a06, a04));
        l0 += pe0;
        acc0.x += pe0 * v0.x; acc0.y += pe0 * v0.y;
        acc0.z += pe0 * v0.z; acc0.w += pe0 * v0.w;
    }
    float rl = 1.f / (l0 + l1);
    float4 b = bias4[lane];
    float4 o = make_float4(fmaxf((acc0.x + acc1.x) * rl + b.x, 0.f),
                           fmaxf((acc0.y + acc1.y) * rl + b.y, 0.f),
                           fmaxf((acc0.z + acc1.z) * rl + b.z, 0.f),
                           fmaxf((acc0.w + acc1.w) * rl + b.w, 0.f));
    size_t oidx = (size_t)node * 64 + lane;
    if (mode) {
        short4 h4, l4;
        split1(o.x, h4.x, l4.x);
        split1(o.y, h4.y, l4.y);
        split1(o.z, h4.z, l4.z);
        split1(o.w, h4.w, l4.w);
        Ahi[oidx] = h4;
        Alo[oidx] = l4;
    } else {
        Hout[oidx] = o;
    }
}

// ---------------- pooling + FC ----------------

__global__ void zero_f(float* p, int n) {
    int i = blockIdx.x * blockDim.x + threadIdx.x;
    if (i < n) p[i] = 0.f;
}

__global__ __launch_bounds__(256) void colsum_kernel(const float* __restrict__ Hmat,
                                                     float* __restrict__ g, int n) {
    int ch = threadIdx.x;
    float s = 0.f;
    for (int r = blockIdx.x; r < n; r += gridDim.x)
        s += Hmat[(size_t)r * HC + ch];
    atomicAdd(&g[ch], s);
}

__global__ __launch_bounds__(256) void fc_kernel(const float* __restrict__ g,
                                                 const float* __restrict__ Wfc,
                                                 const float* __restrict__ bfc,
                                                 float* __restrict__ out, float invN) {
    int t = threadIdx.x;
    float gv = g[t] * invN;
    float p0 = gv * Wfc[2 * t];
    float p1 = gv * Wfc[2 * t + 1];
    #pragma unroll
    for (int off = 32; off > 0; off >>= 1) {
        p0 += __shfl_xor(p0, off, 64);
        p1 += __shfl_xor(p1, off, 64);
    }
    __shared__ float s0[4], s1[4];
    if ((t & 63) == 0) { s0[t >> 6] = p0; s1[t >> 6] = p1; }
    __syncthreads();
    if (t == 0) {
        out[0] = s0[0] + s0[1] + s0[2] + s0[3] + bfc[0];
        out[1] = s1[0] + s1[1] + s1[2] + s1[3] + bfc[1];
    }
}

// ---------------- launch ----------------

extern "C" void kernel_launch(void* const* d_in, const int* in_sizes, int n_in,
                              void* d_out, int out_size, void* d_ws, size_t ws_size,
                              hipStream_t stream) {
    const float* x    = (const float*)d_in[0];
    const int*   eidx = (const int*)d_in[1];   // (2,E) row-major: [src | dst]
    const float* Wl1  = (const float*)d_in[2];
    const float* Wr1  = (const float*)d_in[3];
    const float* att1 = (const float*)d_in[4];
    const float* b1   = (const float*)d_in[5];
    const float* Wl2  = (const float*)d_in[6];
    const float* Wr2  = (const float*)d_in[7];
    const float* att2 = (const float*)d_in[8];
    const float* b2   = (const float*)d_in[9];
    const float* Wfc  = (const float*)d_in[10];
    const float* bfc  = (const float*)d_in[11];
    float* out = (float*)d_out;

    const int* srcv = eidx;
    const int* dstv = eidx + Ee;

    // workspace layout (~75 MB)
    size_t NHC = (size_t)Nn * HC;
    float* XR = (float*)d_ws;
    float* Hb = XR + NHC;
    float* g  = Hb + NHC;
    unsigned short* XLh = (unsigned short*)(g + HC);
    short* Ah   = (short*)(XLh + NHC);
    short* Al   = Ah + NHC;
    short* WhT1 = Al + NHC;                    // 512*256 concat [Wl|Wr]^T per layer
    short* WlT1 = WhT1 + 512 * 256;
    short* WhT2 = WlT1 + 512 * 256;
    short* WlT2 = WhT2 + 512 * 256;
    int* deg       = (int*)(WlT2 + 512 * 256);
    int* row_start = deg + Nn;
    int* cursor    = row_start + (Nn + 1);
    int* colx      = cursor + Nn;              // Ee + Nn entries
    int* bsum      = colx + (Ee + Nn);
    int* boff      = bsum + 128;               // NB+1 entries

    const int NB = (Nn + 255) / 256;           // 79
    const int N4 = (int)(NHC / 4);

    // CSR build
    init_deg<<<(Nn + 255) / 256, 256, 0, stream>>>(deg, Nn);
    hist_kernel<<<(Ee + 255) / 256, 256, 0, stream>>>(dstv, Ee, deg);
    scan1<<<NB, 256, 0, stream>>>(deg, row_start, bsum, Nn);
    scan2<<<1, 64, 0, stream>>>(bsum, boff, NB);
    scan_add<<<(Nn + 256) / 256, 256, 0, stream>>>(row_start, cursor, boff, Nn, NB);
    scatter_kernel<<<(Ee + Nn + 255) / 256, 256, 0, stream>>>(srcv, dstv, Ee, Nn, cursor, colx);

    dim3 ggrid(4, (Nn + 127) / 128);           // 4 x 157

    // weight prep (both layers, one dispatch) + layer-1 input split
    wsplit_all<<<1024, 256, 0, stream>>>(Wl1, Wr1, Wl2, Wr2, WhT1, WlT1, WhT2, WlT2);
    split_kernel<<<(N4 + 255) / 256, 256, 0, stream>>>(x, Ah, Al, N4);

    // layer 1 (gat writes bf16 split directly -> layer-2 GEMM input)
    mfma_gemm<<<ggrid, 256, 0, stream>>>(Ah, Al, WhT1, WlT1, XLh, XR);
    gat_kernel<<<Nn / 4, 256, 0, stream>>>((const ushort4*)XLh, (const float4*)XR,
                                           row_start, colx, (const float4*)att1,
                                           (const float4*)b1, (float4*)Hb,
                                           (short4*)Ah, (short4*)Al, 1);

    // layer 2
    mfma_gemm<<<ggrid, 256, 0, stream>>>(Ah, Al, WhT2, WlT2, XLh, XR);
    gat_kernel<<<Nn / 4, 256, 0, stream>>>((const ushort4*)XLh, (const float4*)XR,
                                           row_start, colx, (const float4*)att2,
                                           (const float4*)b2, (float4*)Hb,
                                           (short4*)Ah, (short4*)Al, 0);

    // pool + fc
    zero_f<<<1, 256, 0, stream>>>(g, HC);
    colsum_kernel<<<256, 256, 0, stream>>>(Hb, g, Nn);
    fc_kernel<<<1, 256, 0, stream>>>(g, Wfc, bfc, out, 1.0f / Nn);
}